// Round 8
// baseline (2363.015 us; speedup 1.0000x reference)
//
#include <hip/hip_runtime.h>
#include <hip/hip_bf16.h>
#include <math.h>

#define LDB 320   // XSmix row: k = m*64+dh (m=0 id, 1..3 = T_m), 256..259 = x,Tx; pad->320

typedef __attribute__((ext_vector_type(8))) short bf16x8;
typedef __attribute__((ext_vector_type(4))) float f32x4;

__device__ __forceinline__ float b2f(short s) {
  unsigned u = ((unsigned)(unsigned short)s) << 16;
  return __uint_as_float(u);
}
__device__ __forceinline__ short f2bh(float x) {
  __hip_bfloat16 h = __float2bfloat16(x);
  return *(short*)&h;
}
__device__ __forceinline__ void f2b2(float x, short& hi, short& lo) {
  hi = f2bh(x);
  lo = f2bh(x - b2f(hi));
}

#define GLOAD(src, dst) \
  __builtin_amdgcn_global_load_lds( \
      (const __attribute__((address_space(1))) void*)(src), \
      (__attribute__((address_space(3))) void*)(dst), 16, 0, 0)

#define MFMA3(A_h, A_l, B_h, B_l, ACC) \
  ACC = __builtin_amdgcn_mfma_f32_16x16x32_bf16(A_h, B_h, ACC, 0, 0, 0); \
  ACC = __builtin_amdgcn_mfma_f32_16x16x32_bf16(A_l, B_h, ACC, 0, 0, 0); \
  ACC = __builtin_amdgcn_mfma_f32_16x16x32_bf16(A_h, B_l, ACC, 0, 0, 0);

// ---------------- utility kernels ----------------
__global__ void k_zeroxt(uint4* a, uint4* b, int n) {
  int i = blockIdx.x * 256 + threadIdx.x;
  if (i < n) { a[i] = (uint4){0,0,0,0}; b[i] = (uint4){0,0,0,0}; }
}

// zero only the m0 slots (k 0..63) of every XS row
__global__ void k_zerom0(short* __restrict__ XShi, short* __restrict__ XSlo) {
  int i = blockIdx.x * 256 + threadIdx.x;
  if (i >= 16384 * 8) return;
  int row = i >> 3, ch = i & 7;
  size_t o = (size_t)row * LDB + ch * 8;
  *(uint4*)(XShi + o) = (uint4){0,0,0,0};
  *(uint4*)(XSlo + o) = (uint4){0,0,0,0};
}

__global__ void k_prepT(const float* __restrict__ S, short* __restrict__ hi,
                        short* __restrict__ lo, int n) {
  int i = blockIdx.x * 256 + threadIdx.x;
  if (i >= n) return;
  short h, l; f2b2(S[i], h, l);
  hi[i] = h; lo[i] = l;
}

__global__ void k_cheb2b(float* __restrict__ AA, short* __restrict__ hi,
                         short* __restrict__ lo) {
  int i = blockIdx.x * 256 + threadIdx.x;
  if (i >= 512 * 512) return;
  int r = i >> 9, c = i & 511;
  float v = 2.f * AA[i] - (r == c ? 1.f : 0.f);
  AA[i] = v;
  short h, l; f2b2(v, h, l);
  hi[i] = h; lo[i] = l;
}

__global__ void k_cheb3b(const float* __restrict__ AT2, const float* __restrict__ A,
                         short* __restrict__ hi, short* __restrict__ lo) {
  int i = blockIdx.x * 256 + threadIdx.x;
  if (i >= 512 * 512) return;
  float v = 2.f * AT2[i] - A[i];
  short h, l; f2b2(v, h, l);
  hi[i] = h; lo[i] = l;
}

// transpose + split a 512x512 f32 matrix -> [c][r] bf16 hi/lo
__global__ __launch_bounds__(256) void t512(const float* __restrict__ in,
                                            short* __restrict__ ohi,
                                            short* __restrict__ olo) {
  __shared__ float t[32][33];
  int c0 = blockIdx.x * 32, r0 = blockIdx.y * 32;
  int tid = threadIdx.x;
  int cc = tid & 31, rr = tid >> 5;
#pragma unroll
  for (int p = 0; p < 4; ++p)
    t[rr + p * 8][cc] = in[(size_t)(r0 + rr + p * 8) * 512 + c0 + cc];
  __syncthreads();
#pragma unroll
  for (int p = 0; p < 4; ++p) {
    int c = rr + p * 8, r = cc;
    short h, l; f2b2(t[r][c], h, l);
    size_t o = (size_t)(c0 + c) * 512 + r0 + r;
    ohi[o] = h; olo[o] = l;
  }
}

// Wt[j][k]: k<256 -> W[(1+(k&63))*4 + (k>>6)][j]; k 256..259 -> W[k-256][j]; else 0
__global__ void k_prepW(const float* __restrict__ W, short* __restrict__ hi,
                        short* __restrict__ lo, int J) {
  int i = blockIdx.x * 256 + threadIdx.x;
  if (i >= J * LDB) return;
  int j = i / LDB, k = i - j * LDB;
  float v = 0.f;
  if (k < 256) {
    int m = k >> 6, dh = k & 63;
    v = W[(size_t)((1 + dh) * 4 + m) * J + j];
  } else if (k < 260) {
    v = W[(size_t)(k - 256) * J + j];
  }
  short h, l; f2b2(v, h, l);
  hi[i] = h; lo[i] = l;
}

// x(t=0) -> Xt x-rows (2048+b) and XS k=256
__global__ void k_setx0(const float* __restrict__ inp, short* __restrict__ Xthi,
                        short* __restrict__ Xtlo, short* __restrict__ XShi,
                        short* __restrict__ XSlo) {
  int i = blockIdx.x * 256 + threadIdx.x;
  if (i >= 32 * 512) return;
  int b = i >> 9, n = i & 511;
  float x = inp[(size_t)b * 6144 + n];
  short h, l; f2b2(x, h, l);
  size_t o = ((size_t)(2048 + b)) * 512 + n;
  Xthi[o] = h; Xtlo[o] = l;
  size_t o2 = ((size_t)(b * 512 + n)) * LDB + 256;
  XShi[o2] = h; XSlo[o2] = l;
}

// ---------------- split GEMM, BM=128 BN=64 BK=32, hi->LDS dbuf, lo->reg direct ---
// C = (Ahi+Alo) @ (Bhi+Blo)^T ; A rows [*,512], B rows [*,512]. 4 waves, 64x32/wave.
// mode 0: C f32 [ldc].  mode 1: XSmix epilogue (h-rows m=1..3; x-block -> 257+mq).
__global__ __launch_bounds__(256) void gemm_bt(
    const short* __restrict__ Ahi, const short* __restrict__ Alo,
    const short* __restrict__ Bhi, const short* __restrict__ Blo,
    float* __restrict__ Cf, int ldc,
    short* __restrict__ XShi, short* __restrict__ XSlo, int mode) {
  __shared__ short smem[17920];  // loop: 2 bufs x (Ah 4096 | Bh 2048); epi: 64x140 u32
  int tid = threadIdx.x, lane = tid & 63, wid = tid >> 6;
  // bijective XCD-chunk swizzle (all grids divisible by 8)
  int nwg = gridDim.x * gridDim.y;
  int lin = blockIdx.y * gridDim.x + blockIdx.x;
  int swz = (lin & 7) * (nwg >> 3) + (lin >> 3);
  int bx = swz % gridDim.x, by = swz / gridDim.x;
  int r0 = by * 128, c0 = bx * 64;
  int wr = wid >> 1, wc = wid & 1;
  int l15 = lane & 15, l4 = lane >> 4;

  f32x4 acc[4][2];
#pragma unroll
  for (int i = 0; i < 4; ++i)
#pragma unroll
    for (int j = 0; j < 2; ++j) acc[i][j] = (f32x4){0.f, 0.f, 0.f, 0.f};

  int aoff[2];
#pragma unroll
  for (int q = 0; q < 2; ++q) {
    int r = (wid * 2 + q) * 16 + (lane >> 2);
    aoff[q] = (r0 + r) * 512 + (((lane & 3) ^ (r & 3)) * 8);
  }
  int rB = wid * 16 + (lane >> 2);
  int boff = (c0 + rB) * 512 + (((lane & 3) ^ (rB & 3)) * 8);

  int afr[4], bfr[2];
  const short* pAlo[4];
  const short* pBlo[2];
#pragma unroll
  for (int fm = 0; fm < 4; ++fm) {
    int ra = wr * 64 + fm * 16 + l15;
    afr[fm] = ra * 32 + ((l4 ^ (ra & 3)) * 8);
    pAlo[fm] = Alo + (size_t)(r0 + ra) * 512 + l4 * 8;
  }
#pragma unroll
  for (int fn = 0; fn < 2; ++fn) {
    int rb = wc * 32 + fn * 16 + l15;
    bfr[fn] = rb * 32 + ((l4 ^ (rb & 3)) * 8);
    pBlo[fn] = Blo + (size_t)(c0 + rb) * 512 + l4 * 8;
  }

  // prologue: stage hi buf0, load lo regs step0
  GLOAD(Ahi + aoff[0], smem + (wid * 2) * 512);
  GLOAD(Ahi + aoff[1], smem + (wid * 2 + 1) * 512);
  GLOAD(Bhi + boff, smem + 4096 + wid * 512);
  bf16x8 alc[4], blc[2];
#pragma unroll
  for (int fm = 0; fm < 4; ++fm) alc[fm] = *(const bf16x8*)(pAlo[fm]);
#pragma unroll
  for (int fn = 0; fn < 2; ++fn) blc[fn] = *(const bf16x8*)(pBlo[fn]);
  __syncthreads();

  int cur = 0;
#pragma unroll
  for (int t = 0; t < 16; ++t) {
    const short* cb = smem + cur * 6144;
    bf16x8 aln[4], bln[2];
    if (t < 15) {
      short* nb = smem + (cur ^ 1) * 6144;
      int k0 = (t + 1) * 32;
      GLOAD(Ahi + aoff[0] + k0, nb + (wid * 2) * 512);
      GLOAD(Ahi + aoff[1] + k0, nb + (wid * 2 + 1) * 512);
      GLOAD(Bhi + boff + k0, nb + 4096 + wid * 512);
#pragma unroll
      for (int fm = 0; fm < 4; ++fm) aln[fm] = *(const bf16x8*)(pAlo[fm] + k0);
#pragma unroll
      for (int fn = 0; fn < 2; ++fn) bln[fn] = *(const bf16x8*)(pBlo[fn] + k0);
    }
    bf16x8 ah[4], bh[2];
#pragma unroll
    for (int fm = 0; fm < 4; ++fm) ah[fm] = *(const bf16x8*)&cb[afr[fm]];
#pragma unroll
    for (int fn = 0; fn < 2; ++fn) bh[fn] = *(const bf16x8*)&cb[4096 + bfr[fn]];
#pragma unroll
    for (int fm = 0; fm < 4; ++fm)
#pragma unroll
      for (int fn = 0; fn < 2; ++fn) {
        MFMA3(ah[fm], alc[fm], bh[fn], blc[fn], acc[fm][fn]);
      }
    __syncthreads();
    if (t < 15) {
#pragma unroll
      for (int fm = 0; fm < 4; ++fm) alc[fm] = aln[fm];
#pragma unroll
      for (int fn = 0; fn < 2; ++fn) blc[fn] = bln[fn];
    }
    cur ^= 1;
  }

  if (mode == 0) {
#pragma unroll
    for (int fm = 0; fm < 4; ++fm)
#pragma unroll
      for (int fn = 0; fn < 2; ++fn) {
        int row = r0 + wr * 64 + fm * 16 + l4 * 4;
        int col = c0 + wc * 32 + fn * 16 + l15;
#pragma unroll
        for (int rr = 0; rr < 4; ++rr)
          Cf[(size_t)(row + rr) * ldc + col] = acc[fm][fn][rr];
      }
  } else {
    // pack hi|lo into u32, LDS-transpose, then coalesced 8-B global stores.
    unsigned* uT = (unsigned*)smem;  // [64 n][140 r]
#pragma unroll
    for (int fm = 0; fm < 4; ++fm)
#pragma unroll
      for (int fn = 0; fn < 2; ++fn) {
        int nl = wc * 32 + fn * 16 + l15;
        int rbase = wr * 64 + fm * 16 + l4 * 4;
        unsigned pk[4];
#pragma unroll
        for (int rr = 0; rr < 4; ++rr) {
          short h, l; f2b2(acc[fm][fn][rr], h, l);
          pk[rr] = (unsigned)(unsigned short)h | ((unsigned)(unsigned short)l << 16);
        }
        uint2 w0; w0.x = pk[0]; w0.y = pk[1];
        uint2 w1; w1.x = pk[2]; w1.y = pk[3];
        *(uint2*)&uT[nl * 140 + rbase] = w0;
        *(uint2*)&uT[nl * 140 + rbase + 2] = w1;
      }
    __syncthreads();
    int mq = bx >> 3, n0s = (bx & 7) * 64;
    if (r0 < 2048) {
      int b0 = r0 >> 6;
#pragma unroll
      for (int l = 0; l < 8; ++l) {
        int e = tid + l * 256;
        int ch = e & 15, bg = (e >> 4) & 1, nl = e >> 5;
        uint4 v = *(const uint4*)&uT[nl * 140 + bg * 64 + ch * 4];
        uint2 hi2, lo2;
        hi2.x = (v.x & 0xffffu) | (v.y << 16);
        hi2.y = (v.z & 0xffffu) | (v.w << 16);
        lo2.x = (v.x >> 16) | (v.y & 0xffff0000u);
        lo2.y = (v.z >> 16) | (v.w & 0xffff0000u);
        size_t dst = ((size_t)((b0 + bg) * 512 + n0s + nl)) * LDB + (mq + 1) * 64 + ch * 4;
        *(uint2*)(XShi + dst) = hi2;
        *(uint2*)(XSlo + dst) = lo2;
      }
    } else {
#pragma unroll
      for (int l = 0; l < 8; ++l) {
        int e = tid + l * 256;
        int nl = e & 63, b = e >> 6;
        unsigned v = uT[nl * 140 + b];
        size_t dst = ((size_t)(b * 512 + n0s + nl)) * LDB + 257 + mq;
        XShi[dst] = (short)(v & 0xffffu);
        XSlo[dst] = (short)(v >> 16);
      }
    }
  }
}

// ---------------- mix GEMM (ru): 128j x 64n per block, K=256 + f32 x-term -------
__global__ __launch_bounds__(256) void k_mix_ru(
    const short* __restrict__ Whi, const short* __restrict__ Wlo,   // [128,320]
    short* __restrict__ XShi, short* __restrict__ XSlo,             // read + m0 write
    const float* __restrict__ bias,                                 // [128]
    const short* __restrict__ Xthi, const short* __restrict__ Xtlo, // h-old rows
    short* __restrict__ X2hi, short* __restrict__ X2lo,             // r*h rows
    float* __restrict__ Ut) {
  __shared__ short smem[2 * 6144];  // per buf: Wh 4096 | XSh 2048
  __shared__ float wx[128][4];
  __shared__ float xv[64][4];
  int tid = threadIdx.x, lane = tid & 63, wid = tid >> 6;
  int n0 = blockIdx.x * 64, b = blockIdx.y;
  int wr = wid >> 1, wc = wid & 1;
  int l15 = lane & 15, l4 = lane >> 4;

  if (tid < 128) {
#pragma unroll
    for (int m = 0; m < 4; ++m)
      wx[tid][m] = b2f(Whi[tid * LDB + 256 + m]) + b2f(Wlo[tid * LDB + 256 + m]);
  } else if (tid < 192) {
    int nl = tid - 128;
    size_t o = ((size_t)(b * 512 + n0 + nl)) * LDB + 256;
#pragma unroll
    for (int m = 0; m < 4; ++m)
      xv[nl][m] = b2f(XShi[o + m]) + b2f(XSlo[o + m]);
  }

  f32x4 acc[4][2];
#pragma unroll
  for (int i = 0; i < 4; ++i)
#pragma unroll
    for (int j = 0; j < 2; ++j) acc[i][j] = (f32x4){0.f, 0.f, 0.f, 0.f};

  int aoff[2];
#pragma unroll
  for (int q = 0; q < 2; ++q) {
    int r = (wid * 2 + q) * 16 + (lane >> 2);
    aoff[q] = r * LDB + (((lane & 3) ^ (r & 3)) * 8);
  }
  int rB = wid * 16 + (lane >> 2);
  size_t boff = ((size_t)(b * 512 + n0 + rB)) * LDB + (((lane & 3) ^ (rB & 3)) * 8);

  int afr[4], bfr[2];
  const short* pAlo[4];
  const short* pBlo[2];
#pragma unroll
  for (int fm = 0; fm < 4; ++fm) {
    int ra = wr * 64 + fm * 16 + l15;
    afr[fm] = ra * 32 + ((l4 ^ (ra & 3)) * 8);
    pAlo[fm] = Wlo + (size_t)ra * LDB + l4 * 8;
  }
#pragma unroll
  for (int fn = 0; fn < 2; ++fn) {
    int rb = wc * 32 + fn * 16 + l15;
    bfr[fn] = rb * 32 + ((l4 ^ (rb & 3)) * 8);
    pBlo[fn] = XSlo + ((size_t)(b * 512 + n0 + rb)) * LDB + l4 * 8;
  }

  GLOAD(Whi + aoff[0], smem + (wid * 2) * 512);
  GLOAD(Whi + aoff[1], smem + (wid * 2 + 1) * 512);
  GLOAD(XShi + boff, smem + 4096 + wid * 512);
  bf16x8 alc[4], blc[2];
#pragma unroll
  for (int fm = 0; fm < 4; ++fm) alc[fm] = *(const bf16x8*)(pAlo[fm]);
#pragma unroll
  for (int fn = 0; fn < 2; ++fn) blc[fn] = *(const bf16x8*)(pBlo[fn]);
  __syncthreads();

  int cur = 0;
#pragma unroll
  for (int t = 0; t < 8; ++t) {
    const short* cb = smem + cur * 6144;
    bf16x8 aln[4], bln[2];
    if (t < 7) {
      short* nb = smem + (cur ^ 1) * 6144;
      int k0 = (t + 1) * 32;
      GLOAD(Whi + aoff[0] + k0, nb + (wid * 2) * 512);
      GLOAD(Whi + aoff[1] + k0, nb + (wid * 2 + 1) * 512);
      GLOAD(XShi + boff + k0, nb + 4096 + wid * 512);
#pragma unroll
      for (int fm = 0; fm < 4; ++fm) aln[fm] = *(const bf16x8*)(pAlo[fm] + k0);
#pragma unroll
      for (int fn = 0; fn < 2; ++fn) bln[fn] = *(const bf16x8*)(pBlo[fn] + k0);
    }
    bf16x8 ah[4], bh[2];
#pragma unroll
    for (int fm = 0; fm < 4; ++fm) ah[fm] = *(const bf16x8*)&cb[afr[fm]];
#pragma unroll
    for (int fn = 0; fn < 2; ++fn) bh[fn] = *(const bf16x8*)&cb[4096 + bfr[fn]];
#pragma unroll
    for (int fm = 0; fm < 4; ++fm)
#pragma unroll
      for (int fn = 0; fn < 2; ++fn) {
        MFMA3(ah[fm], alc[fm], bh[fn], blc[fn], acc[fm][fn]);
      }
    __syncthreads();
    if (t < 7) {
#pragma unroll
      for (int fm = 0; fm < 4; ++fm) alc[fm] = aln[fm];
#pragma unroll
      for (int fn = 0; fn < 2; ++fn) blc[fn] = bln[fn];
    }
    cur ^= 1;
  }

#pragma unroll
  for (int fm = 0; fm < 4; ++fm)
#pragma unroll
    for (int fn = 0; fn < 2; ++fn) {
      int nl = wc * 32 + fn * 16 + l15;
      int ng = n0 + nl;
      int jb = wr * 64 + fm * 16 + l4 * 4;
      if (wr == 0) {  // r-half: write r*h into X2 + XS m0
        short ph[4], pl[4];
#pragma unroll
        for (int rr = 0; rr < 4; ++rr) {
          int jg = jb + rr;
          float v = acc[fm][fn][rr] + wx[jg][0] * xv[nl][0] + wx[jg][1] * xv[nl][1]
                  + wx[jg][2] * xv[nl][2] + wx[jg][3] * xv[nl][3];
          float rg = 1.f / (1.f + expf(-(v + bias[jg])));
          size_t hrow = ((size_t)(b * 64 + jg)) * 512 + ng;
          float h = b2f(Xthi[hrow]) + b2f(Xtlo[hrow]);
          f2b2(rg * h, ph[rr], pl[rr]);
          X2hi[hrow] = ph[rr]; X2lo[hrow] = pl[rr];
        }
        size_t dst = ((size_t)(b * 512 + ng)) * LDB + jb;
        uint2 h2, l2;
        h2.x = (unsigned)(unsigned short)ph[0] | ((unsigned)(unsigned short)ph[1] << 16);
        h2.y = (unsigned)(unsigned short)ph[2] | ((unsigned)(unsigned short)ph[3] << 16);
        l2.x = (unsigned)(unsigned short)pl[0] | ((unsigned)(unsigned short)pl[1] << 16);
        l2.y = (unsigned)(unsigned short)pl[2] | ((unsigned)(unsigned short)pl[3] << 16);
        *(uint2*)(XShi + dst) = h2;
        *(uint2*)(XSlo + dst) = l2;
      } else {  // u-half
#pragma unroll
        for (int rr = 0; rr < 4; ++rr) {
          int jg = jb + rr;  // 64..127
          float v = acc[fm][fn][rr] + wx[jg][0] * xv[nl][0] + wx[jg][1] * xv[nl][1]
                  + wx[jg][2] * xv[nl][2] + wx[jg][3] * xv[nl][3];
          float u = 1.f / (1.f + expf(-(v + bias[jg])));
          Ut[((size_t)(b * 64 + (jg - 64))) * 512 + ng] = u;
        }
      }
    }
}

// ---------------- mix GEMM (c): 64j x 64n per block; tanh + GRU + decoder out ---
__global__ __launch_bounds__(256) void k_mix_c(
    const short* __restrict__ Whi, const short* __restrict__ Wlo,   // [64,320]
    short* __restrict__ XShi, short* __restrict__ XSlo,             // read + m0/x write
    const float* __restrict__ bias,                                 // [64]
    const float* __restrict__ Ut,
    short* __restrict__ Xthi, short* __restrict__ Xtlo,             // h rows + x rows
    int dmode, const float* __restrict__ xsrc,
    const float* __restrict__ Wo, const float* __restrict__ bo,
    float* __restrict__ dout, int step) {
  __shared__ short smem[2 * 4096];  // per buf: Wh 2048 | XSh 2048
  __shared__ float wx[64][4];
  __shared__ float xv[64][4];
  __shared__ float hls[64][66];
  int tid = threadIdx.x, lane = tid & 63, wid = tid >> 6;
  int n0 = blockIdx.x * 64, b = blockIdx.y;
  int wr = wid >> 1, wc = wid & 1;
  int l15 = lane & 15, l4 = lane >> 4;

  if (tid < 64) {
#pragma unroll
    for (int m = 0; m < 4; ++m)
      wx[tid][m] = b2f(Whi[tid * LDB + 256 + m]) + b2f(Wlo[tid * LDB + 256 + m]);
  } else if (tid < 128) {
    int nl = tid - 64;
    size_t o = ((size_t)(b * 512 + n0 + nl)) * LDB + 256;
#pragma unroll
    for (int m = 0; m < 4; ++m)
      xv[nl][m] = b2f(XShi[o + m]) + b2f(XSlo[o + m]);
  }

  f32x4 acc[2][2];
#pragma unroll
  for (int i = 0; i < 2; ++i)
#pragma unroll
    for (int j = 0; j < 2; ++j) acc[i][j] = (f32x4){0.f, 0.f, 0.f, 0.f};

  int rA = wid * 16 + (lane >> 2);
  int aoff = rA * LDB + (((lane & 3) ^ (rA & 3)) * 8);
  size_t boff = ((size_t)(b * 512 + n0 + rA)) * LDB + (((lane & 3) ^ (rA & 3)) * 8);

  int afr[2], bfr[2];
  const short* pAlo[2];
  const short* pBlo[2];
#pragma unroll
  for (int fm = 0; fm < 2; ++fm) {
    int ra = wr * 32 + fm * 16 + l15;
    afr[fm] = ra * 32 + ((l4 ^ (ra & 3)) * 8);
    pAlo[fm] = Wlo + (size_t)ra * LDB + l4 * 8;
  }
#pragma unroll
  for (int fn = 0; fn < 2; ++fn) {
    int rb = wc * 32 + fn * 16 + l15;
    bfr[fn] = rb * 32 + ((l4 ^ (rb & 3)) * 8);
    pBlo[fn] = XSlo + ((size_t)(b * 512 + n0 + rb)) * LDB + l4 * 8;
  }

  GLOAD(Whi + aoff, smem + wid * 512);
  GLOAD(XShi + boff, smem + 2048 + wid * 512);
  bf16x8 alc[2], blc[2];
#pragma unroll
  for (int fm = 0; fm < 2; ++fm) alc[fm] = *(const bf16x8*)(pAlo[fm]);
#pragma unroll
  for (int fn = 0; fn < 2; ++fn) blc[fn] = *(const bf16x8*)(pBlo[fn]);
  __syncthreads();

  int cur = 0;
#pragma unroll
  for (int t = 0; t < 8; ++t) {
    const short* cb = smem + cur * 4096;
    bf16x8 aln[2], bln[2];
    if (t < 7) {
      short* nb = smem + (cur ^ 1) * 4096;
      int k0 = (t + 1) * 32;
      GLOAD(Whi + aoff + k0, nb + wid * 512);
      GLOAD(XShi + boff + k0, nb + 2048 + wid * 512);
#pragma unroll
      for (int fm = 0; fm < 2; ++fm) aln[fm] = *(const bf16x8*)(pAlo[fm] + k0);
#pragma unroll
      for (int fn = 0; fn < 2; ++fn) bln[fn] = *(const bf16x8*)(pBlo[fn] + k0);
    }
    bf16x8 ah[2], bh[2];
#pragma unroll
    for (int fm = 0; fm < 2; ++fm) ah[fm] = *(const bf16x8*)&cb[afr[fm]];
#pragma unroll
    for (int fn = 0; fn < 2; ++fn) bh[fn] = *(const bf16x8*)&cb[2048 + bfr[fn]];
#pragma unroll
    for (int fm = 0; fm < 2; ++fm)
#pragma unroll
      for (int fn = 0; fn < 2; ++fn) {
        MFMA3(ah[fm], alc[fm], bh[fn], blc[fn], acc[fm][fn]);
      }
    __syncthreads();
    if (t < 7) {
#pragma unroll
      for (int fm = 0; fm < 2; ++fm) alc[fm] = aln[fm];
#pragma unroll
      for (int fn = 0; fn < 2; ++fn) blc[fn] = bln[fn];
    }
    cur ^= 1;
  }

#pragma unroll
  for (int fm = 0; fm < 2; ++fm)
#pragma unroll
    for (int fn = 0; fn < 2; ++fn) {
      int nl = wc * 32 + fn * 16 + l15;
      int ng = n0 + nl;
      int jb = wr * 32 + fm * 16 + l4 * 4;
      short ph[4], pl[4];
#pragma unroll
      for (int rr = 0; rr < 4; ++rr) {
        int jg = jb + rr;
        float v = acc[fm][fn][rr] + wx[jg][0] * xv[nl][0] + wx[jg][1] * xv[nl][1]
                + wx[jg][2] * xv[nl][2] + wx[jg][3] * xv[nl][3];
        float cv = tanhf(v + bias[jg]);
        size_t hrow = ((size_t)(b * 64 + jg)) * 512 + ng;
        float u = Ut[hrow];
        float h = b2f(Xthi[hrow]) + b2f(Xtlo[hrow]);
        float hn = u * h + (1.f - u) * cv;
        f2b2(hn, ph[rr], pl[rr]);
        Xthi[hrow] = ph[rr]; Xtlo[hrow] = pl[rr];
        hls[jg][nl] = hn;
      }
      size_t dst = ((size_t)(b * 512 + ng)) * LDB + jb;
      uint2 h2, l2;
      h2.x = (unsigned)(unsigned short)ph[0] | ((unsigned)(unsigned short)ph[1] << 16);
      h2.y = (unsigned)(unsigned short)ph[2] | ((unsigned)(unsigned short)ph[3] << 16);
      l2.x = (unsigned)(unsigned short)pl[0] | ((unsigned)(unsigned short)pl[1] << 16);
      l2.y = (unsigned)(unsigned short)pl[2] | ((unsigned)(unsigned short)pl[3] << 16);
      *(uint2*)(XShi + dst) = h2;
      *(uint2*)(XSlo + dst) = l2;
    }

  __syncthreads();
  if (dmode) {
    if (tid < 64) {
      int ng = n0 + tid;
      float s = bo[0];
#pragma unroll
      for (int j = 0; j < 64; ++j) s += hls[j][tid] * Wo[j];
      dout[((size_t)b * 12 + step) * 512 + ng] = s;
      short hh, ll; f2b2(s, hh, ll);
      size_t o = ((size_t)(2048 + b)) * 512 + ng;
      Xthi[o] = hh; Xtlo[o] = ll;
      size_t o2 = ((size_t)(b * 512 + ng)) * LDB + 256;
      XShi[o2] = hh; XSlo[o2] = ll;
    }
  } else {
    if (tid < 64) {
      int ng = n0 + tid;
      float x = xsrc ? xsrc[(size_t)b * 6144 + ng] : 0.f;
      short hh, ll; f2b2(x, hh, ll);
      size_t o = ((size_t)(2048 + b)) * 512 + ng;
      Xthi[o] = hh; Xtlo[o] = ll;
      size_t o2 = ((size_t)(b * 512 + ng)) * LDB + 256;
      XShi[o2] = hh; XSlo[o2] = ll;
    }
  }
}

extern "C" void kernel_launch(void* const* d_in, const int* in_sizes, int n_in,
                              void* d_out, int out_size, void* d_ws, size_t ws_size,
                              hipStream_t stream) {
  const float* inputs = (const float*)d_in[0];
  const float* graph  = (const float*)d_in[1];
  const float* eWru = (const float*)d_in[2];
  const float* ebru = (const float*)d_in[3];
  const float* eWc  = (const float*)d_in[4];
  const float* ebc  = (const float*)d_in[5];
  const float* dWru = (const float*)d_in[6];
  const float* dbru = (const float*)d_in[7];
  const float* dWc  = (const float*)d_in[8];
  const float* dbc  = (const float*)d_in[9];
  const float* dWo  = (const float*)d_in[10];
  const float* dbo  = (const float*)d_in[11];
  float* out = (float*)d_out;

  char* w = (char*)d_ws;
  auto carve = [&](size_t bytes) {
    char* p = w; w += (bytes + 255) & ~(size_t)255; return p;
  };
  short* Tshi = (short*)carve((size_t)1536 * 512 * 2);
  short* Tslo = (short*)carve((size_t)1536 * 512 * 2);
  short* Xthi = (short*)carve((size_t)2176 * 512 * 2);
  short* Xtlo = (short*)carve((size_t)2176 * 512 * 2);
  short* X2hi = (short*)carve((size_t)2048 * 512 * 2);
  short* X2lo = (short*)carve((size_t)2048 * 512 * 2);
  short* XShi = (short*)carve((size_t)16384 * LDB * 2);
  short* XSlo = (short*)carve((size_t)16384 * LDB * 2);
  float* Ut   = (float*)carve((size_t)2048 * 512 * 4);
  float* TMP  = (float*)carve((size_t)512 * 512 * 4);
  float* TMP2 = (float*)carve((size_t)512 * 512 * 4);
  short* Bthi = (short*)carve((size_t)512 * 512 * 2);
  short* Btlo = (short*)carve((size_t)512 * 512 * 2);
  short* eWruHi = (short*)carve((size_t)128 * LDB * 2);
  short* eWruLo = (short*)carve((size_t)128 * LDB * 2);
  short* eWcHi  = (short*)carve((size_t)64 * LDB * 2);
  short* eWcLo  = (short*)carve((size_t)64 * LDB * 2);
  short* dWruHi = (short*)carve((size_t)128 * LDB * 2);
  short* dWruLo = (short*)carve((size_t)128 * LDB * 2);
  short* dWcHi  = (short*)carve((size_t)64 * LDB * 2);
  short* dWcLo  = (short*)carve((size_t)64 * LDB * 2);
  if ((size_t)(w - (char*)d_ws) > ws_size) return;

  dim3 blk(256);
  // zero h-rows of Xt (h0 = 0) and m0 slots of XS
  k_zeroxt<<<512, blk, 0, stream>>>((uint4*)Xthi, (uint4*)Xtlo, 131072);
  k_zerom0<<<512, blk, 0, stream>>>(XShi, XSlo);

  // T-stack [T1;T2;T3]
  k_prepT<<<1024, blk, 0, stream>>>(graph, Tshi, Tslo, 512 * 512);
  t512<<<dim3(16, 16), blk, 0, stream>>>(graph, Bthi, Btlo);
  gemm_bt<<<dim3(8, 4), blk, 0, stream>>>(Tshi, Tslo, Bthi, Btlo, TMP, 512,
                                          nullptr, nullptr, 0);
  k_cheb2b<<<1024, blk, 0, stream>>>(TMP, Tshi + 512 * 512, Tslo + 512 * 512);
  t512<<<dim3(16, 16), blk, 0, stream>>>(TMP, Bthi, Btlo);
  gemm_bt<<<dim3(8, 4), blk, 0, stream>>>(Tshi, Tslo, Bthi, Btlo, TMP2, 512,
                                          nullptr, nullptr, 0);
  k_cheb3b<<<1024, blk, 0, stream>>>(TMP2, graph, Tshi + 1024 * 512, Tslo + 1024 * 512);

  k_prepW<<<160, blk, 0, stream>>>(eWru, eWruHi, eWruLo, 128);
  k_prepW<<<80,  blk, 0, stream>>>(eWc,  eWcHi,  eWcLo,  64);
  k_prepW<<<160, blk, 0, stream>>>(dWru, dWruHi, dWruLo, 128);
  k_prepW<<<80,  blk, 0, stream>>>(dWc,  dWcHi,  dWcLo,  64);
  k_setx0<<<64, blk, 0, stream>>>(inputs, Xthi, Xtlo, XShi, XSlo);

  dim3 d1Grid(24, 17);  // 1536 cols/64 x (2048 h-rows + x-rows)/128 ; 408 blocks (%8==0)
  dim3 d2Grid(24, 16);  // h-rows only ; 384 blocks (%8==0)
  dim3 mGrid(8, 32);    // 512 n /64 x b

  for (int t = 0; t < 24; ++t) {
    bool enc = t < 12;
    const short* wruh = enc ? eWruHi : dWruHi;
    const short* wrul = enc ? eWruLo : dWruLo;
    const short* wch  = enc ? eWcHi  : dWcHi;
    const short* wcl  = enc ? eWcLo  : dWcLo;
    const float* bru  = enc ? ebru : dbru;
    const float* bc   = enc ? ebc  : dbc;

    gemm_bt<<<d1Grid, blk, 0, stream>>>(Xthi, Xtlo, Tshi, Tslo,
                                        nullptr, 0, XShi, XSlo, 1);
    k_mix_ru<<<mGrid, blk, 0, stream>>>(wruh, wrul, XShi, XSlo, bru,
                                        Xthi, Xtlo, X2hi, X2lo, Ut);
    gemm_bt<<<d2Grid, blk, 0, stream>>>(X2hi, X2lo, Tshi, Tslo,
                                        nullptr, 0, XShi, XSlo, 1);
    if (enc) {
      const float* xs = (t < 11) ? inputs + (size_t)(t + 1) * 512 : nullptr;
      k_mix_c<<<mGrid, blk, 0, stream>>>(wch, wcl, XShi, XSlo, bc, Ut,
                                         Xthi, Xtlo, 0, xs,
                                         nullptr, nullptr, nullptr, 0);
    } else {
      k_mix_c<<<mGrid, blk, 0, stream>>>(wch, wcl, XShi, XSlo, bc, Ut,
                                         Xthi, Xtlo, 1, nullptr,
                                         dWo, dbo, out, t - 12);
    }
  }
}

// Round 9
// 1599.234 us; speedup vs baseline: 1.4776x; 1.4776x over previous
//
#include <hip/hip_runtime.h>
#include <hip/hip_bf16.h>
#include <math.h>

#define LDB 320   // XSmix row: k = m*64+dh (m=0 id, 1..3 = T_m), 256..259 = x,Tx; pad->320
// LDS slot swizzle: period-8 over rows -> 2-way bank aliasing (free) on ds_read_b128.
// MUST be applied identically on the global-source side and the frag-read side.
#define SLOT(c, r) (((c) ^ (((r) >> 1) & 3)) * 8)

typedef __attribute__((ext_vector_type(8))) short bf16x8;
typedef __attribute__((ext_vector_type(4))) float f32x4;

__device__ __forceinline__ float b2f(short s) {
  unsigned u = ((unsigned)(unsigned short)s) << 16;
  return __uint_as_float(u);
}
__device__ __forceinline__ short f2bh(float x) {
  __hip_bfloat16 h = __float2bfloat16(x);
  return *(short*)&h;
}
__device__ __forceinline__ void f2b2(float x, short& hi, short& lo) {
  hi = f2bh(x);
  lo = f2bh(x - b2f(hi));
}

#define GLOAD(src, dst) \
  __builtin_amdgcn_global_load_lds( \
      (const __attribute__((address_space(1))) void*)(src), \
      (__attribute__((address_space(3))) void*)(dst), 16, 0, 0)

// ---------------- utility kernels ----------------
__global__ void k_zeroxt(uint4* a, uint4* b, int n) {
  int i = blockIdx.x * 256 + threadIdx.x;
  if (i < n) { a[i] = (uint4){0,0,0,0}; b[i] = (uint4){0,0,0,0}; }
}

// zero only the m0 slots (k 0..63) of every XS row (h0 = 0); pads never read
__global__ void k_zerom0(short* __restrict__ XShi, short* __restrict__ XSlo) {
  int i = blockIdx.x * 256 + threadIdx.x;
  if (i >= 16384 * 8) return;
  int row = i >> 3, ch = i & 7;
  size_t o = (size_t)row * LDB + ch * 8;
  *(uint4*)(XShi + o) = (uint4){0,0,0,0};
  *(uint4*)(XSlo + o) = (uint4){0,0,0,0};
}

__global__ void k_prepT(const float* __restrict__ S, short* __restrict__ hi,
                        short* __restrict__ lo, int n) {
  int i = blockIdx.x * 256 + threadIdx.x;
  if (i >= n) return;
  short h, l; f2b2(S[i], h, l);
  hi[i] = h; lo[i] = l;
}

__global__ void k_cheb2b(float* __restrict__ AA, short* __restrict__ hi,
                         short* __restrict__ lo) {
  int i = blockIdx.x * 256 + threadIdx.x;
  if (i >= 512 * 512) return;
  int r = i >> 9, c = i & 511;
  float v = 2.f * AA[i] - (r == c ? 1.f : 0.f);
  AA[i] = v;
  short h, l; f2b2(v, h, l);
  hi[i] = h; lo[i] = l;
}

__global__ void k_cheb3b(const float* __restrict__ AT2, const float* __restrict__ A,
                         short* __restrict__ hi, short* __restrict__ lo) {
  int i = blockIdx.x * 256 + threadIdx.x;
  if (i >= 512 * 512) return;
  float v = 2.f * AT2[i] - A[i];
  short h, l; f2b2(v, h, l);
  hi[i] = h; lo[i] = l;
}

// transpose + split a 512x512 f32 matrix -> [c][r] bf16 hi/lo
__global__ __launch_bounds__(256) void t512(const float* __restrict__ in,
                                            short* __restrict__ ohi,
                                            short* __restrict__ olo) {
  __shared__ float t[32][33];
  int c0 = blockIdx.x * 32, r0 = blockIdx.y * 32;
  int tid = threadIdx.x;
  int cc = tid & 31, rr = tid >> 5;
#pragma unroll
  for (int p = 0; p < 4; ++p)
    t[rr + p * 8][cc] = in[(size_t)(r0 + rr + p * 8) * 512 + c0 + cc];
  __syncthreads();
#pragma unroll
  for (int p = 0; p < 4; ++p) {
    int c = rr + p * 8, r = cc;
    short h, l; f2b2(t[r][c], h, l);
    size_t o = (size_t)(c0 + c) * 512 + r0 + r;
    ohi[o] = h; olo[o] = l;
  }
}

// Wt[j][k]: k<256 -> W[(1+(k&63))*4 + (k>>6)][j]; k 256..259 -> W[k-256][j]; else 0
__global__ void k_prepW(const float* __restrict__ W, short* __restrict__ hi,
                        short* __restrict__ lo, int J) {
  int i = blockIdx.x * 256 + threadIdx.x;
  if (i >= J * LDB) return;
  int j = i / LDB, k = i - j * LDB;
  float v = 0.f;
  if (k < 256) {
    int m = k >> 6, dh = k & 63;
    v = W[(size_t)((1 + dh) * 4 + m) * J + j];
  } else if (k < 260) {
    v = W[(size_t)(k - 256) * J + j];
  }
  short h, l; f2b2(v, h, l);
  hi[i] = h; lo[i] = l;
}

// x(t=0) -> Xt x-rows (2048+b) and XS k=256
__global__ void k_setx0(const float* __restrict__ inp, short* __restrict__ Xthi,
                        short* __restrict__ Xtlo, short* __restrict__ XShi,
                        short* __restrict__ XSlo) {
  int i = blockIdx.x * 256 + threadIdx.x;
  if (i >= 32 * 512) return;
  int b = i >> 9, n = i & 511;
  float x = inp[(size_t)b * 6144 + n];
  short h, l; f2b2(x, h, l);
  size_t o = ((size_t)(2048 + b)) * 512 + n;
  Xthi[o] = h; Xtlo[o] = l;
  size_t o2 = ((size_t)(b * 512 + n)) * LDB + 256;
  XShi[o2] = h; XSlo[o2] = l;
}

// ---------------- split GEMM, BM=128 BN=64 BK=32, 2-phase dbuf ----------------
// C = (Ahi+Alo) @ (Bhi+Blo)^T ; A rows [*,512], B rows [*,512].
// mode 0: C f32 [ldc].  mode 1: XSmix epilogue (h-rows m=1..3; x-block -> 257+mq).
__global__ __launch_bounds__(256) void gemm_bt(
    const short* __restrict__ Ahi, const short* __restrict__ Alo,
    const short* __restrict__ Bhi, const short* __restrict__ Blo,
    float* __restrict__ Cf, int ldc,
    short* __restrict__ XShi, short* __restrict__ XSlo, int mode) {
  __shared__ short smem[2 * 12288];  // per buf: Ah 4096 | Al 4096 | Bh 2048 | Bl 2048
  int tid = threadIdx.x, lane = tid & 63, wid = tid >> 6;
  int r0 = blockIdx.y * 128, c0 = blockIdx.x * 64;
  int wr = wid >> 1, wc = wid & 1;
  int l15 = lane & 15, l4 = lane >> 4;

  f32x4 acc[4][2];
#pragma unroll
  for (int i = 0; i < 4; ++i)
#pragma unroll
    for (int j = 0; j < 2; ++j) acc[i][j] = (f32x4){0.f, 0.f, 0.f, 0.f};

  int aoff[2];
#pragma unroll
  for (int q = 0; q < 2; ++q) {
    int r = (wid * 2 + q) * 16 + (lane >> 2);
    aoff[q] = (r0 + r) * 512 + SLOT(lane & 3, r);
  }
  int rB = wid * 16 + (lane >> 2);
  int boff = (c0 + rB) * 512 + SLOT(lane & 3, rB);

  int afr[4], bfr[2];
#pragma unroll
  for (int fm = 0; fm < 4; ++fm) {
    int ra = wr * 64 + fm * 16 + l15;
    afr[fm] = ra * 32 + SLOT(l4, ra);
  }
#pragma unroll
  for (int fn = 0; fn < 2; ++fn) {
    int rb = wc * 32 + fn * 16 + l15;
    bfr[fn] = rb * 32 + SLOT(l4, rb);
  }

#pragma unroll
  for (int q = 0; q < 2; ++q) {
    GLOAD(Ahi + aoff[q], smem + (wid * 2 + q) * 512);
    GLOAD(Alo + aoff[q], smem + 4096 + (wid * 2 + q) * 512);
  }
  GLOAD(Bhi + boff, smem + 8192 + wid * 512);
  GLOAD(Blo + boff, smem + 10240 + wid * 512);
  __syncthreads();

  int cur = 0;
#pragma unroll
  for (int t = 0; t < 16; ++t) {
    const short* cb = smem + cur * 12288;
    if (t < 15) {
      short* nb = smem + (cur ^ 1) * 12288;
      int k0 = (t + 1) * 32;
#pragma unroll
      for (int q = 0; q < 2; ++q) {
        GLOAD(Ahi + aoff[q] + k0, nb + (wid * 2 + q) * 512);
        GLOAD(Alo + aoff[q] + k0, nb + 4096 + (wid * 2 + q) * 512);
      }
      GLOAD(Bhi + boff + k0, nb + 8192 + wid * 512);
      GLOAD(Blo + boff + k0, nb + 10240 + wid * 512);
    }
    bf16x8 ah[4], al[4], bh[2], bl[2];
#pragma unroll
    for (int fm = 0; fm < 4; ++fm) {
      ah[fm] = *(const bf16x8*)&cb[afr[fm]];
      al[fm] = *(const bf16x8*)&cb[4096 + afr[fm]];
    }
#pragma unroll
    for (int fn = 0; fn < 2; ++fn) {
      bh[fn] = *(const bf16x8*)&cb[8192 + bfr[fn]];
      bl[fn] = *(const bf16x8*)&cb[10240 + bfr[fn]];
    }
#pragma unroll
    for (int fm = 0; fm < 4; ++fm)
#pragma unroll
      for (int fn = 0; fn < 2; ++fn) {
        acc[fm][fn] = __builtin_amdgcn_mfma_f32_16x16x32_bf16(ah[fm], bh[fn], acc[fm][fn], 0, 0, 0);
        acc[fm][fn] = __builtin_amdgcn_mfma_f32_16x16x32_bf16(al[fm], bh[fn], acc[fm][fn], 0, 0, 0);
        acc[fm][fn] = __builtin_amdgcn_mfma_f32_16x16x32_bf16(ah[fm], bl[fn], acc[fm][fn], 0, 0, 0);
      }
    __syncthreads();
    cur ^= 1;
  }

  if (mode == 0) {
#pragma unroll
    for (int fm = 0; fm < 4; ++fm)
#pragma unroll
      for (int fn = 0; fn < 2; ++fn) {
        int row = r0 + wr * 64 + fm * 16 + l4 * 4;
        int col = c0 + wc * 32 + fn * 16 + l15;
#pragma unroll
        for (int rr = 0; rr < 4; ++rr)
          Cf[(size_t)(row + rr) * ldc + col] = acc[fm][fn][rr];
      }
  } else {
    // pack hi|lo into u32, LDS-transpose, then coalesced 8-B global stores.
    unsigned* uT = (unsigned*)smem;  // [64 n][140 r] packed hi|lo
#pragma unroll
    for (int fm = 0; fm < 4; ++fm)
#pragma unroll
      for (int fn = 0; fn < 2; ++fn) {
        int nl = wc * 32 + fn * 16 + l15;
        int rbase = wr * 64 + fm * 16 + l4 * 4;
        unsigned pk[4];
#pragma unroll
        for (int rr = 0; rr < 4; ++rr) {
          short h, l; f2b2(acc[fm][fn][rr], h, l);
          pk[rr] = (unsigned)(unsigned short)h | ((unsigned)(unsigned short)l << 16);
        }
        uint2 w0; w0.x = pk[0]; w0.y = pk[1];
        uint2 w1; w1.x = pk[2]; w1.y = pk[3];
        *(uint2*)&uT[nl * 140 + rbase] = w0;
        *(uint2*)&uT[nl * 140 + rbase + 2] = w1;
      }
    __syncthreads();
    int mq = blockIdx.x >> 3;        // 0..2 -> T_{mq+1}
    int n0s = (blockIdx.x & 7) * 64;
    if (r0 < 2048) {
      int b0 = r0 >> 6;
#pragma unroll
      for (int l = 0; l < 8; ++l) {
        int e = tid + l * 256;
        int ch = e & 15, bg = (e >> 4) & 1, nl = e >> 5;
        uint4 v = *(const uint4*)&uT[nl * 140 + bg * 64 + ch * 4];
        uint2 hi2, lo2;
        hi2.x = (v.x & 0xffffu) | (v.y << 16);
        hi2.y = (v.z & 0xffffu) | (v.w << 16);
        lo2.x = (v.x >> 16) | (v.y & 0xffff0000u);
        lo2.y = (v.z >> 16) | (v.w & 0xffff0000u);
        size_t dst = ((size_t)((b0 + bg) * 512 + n0s + nl)) * LDB + (mq + 1) * 64 + ch * 4;
        *(uint2*)(XShi + dst) = hi2;
        *(uint2*)(XSlo + dst) = lo2;
      }
    } else {
#pragma unroll
      for (int l = 0; l < 8; ++l) {
        int e = tid + l * 256;
        int nl = e & 63, b = e >> 6;
        unsigned v = uT[nl * 140 + b];
        size_t dst = ((size_t)(b * 512 + n0s + nl)) * LDB + 257 + mq;
        XShi[dst] = (short)(v & 0xffffu);
        XSlo[dst] = (short)(v >> 16);
      }
    }
  }
}

// ---------------- mix GEMM (ru): K=256 + f32 x-term; sigmoid epilogue ----------
__global__ __launch_bounds__(256) void k_mix_ru(
    const short* __restrict__ Whi, const short* __restrict__ Wlo,   // [128,320]
    short* __restrict__ XShi, short* __restrict__ XSlo,             // read + m0 write
    const float* __restrict__ bias,                                 // [128]
    const short* __restrict__ Xthi, const short* __restrict__ Xtlo, // h-old rows
    short* __restrict__ X2hi, short* __restrict__ X2lo,             // r*h rows
    float* __restrict__ Ut) {
  __shared__ short smem[2 * 12288];
  __shared__ float wx[128][4];
  __shared__ float xv[64][4];
  int tid = threadIdx.x, lane = tid & 63, wid = tid >> 6;
  int n0 = blockIdx.x * 64, b = blockIdx.y;
  int wr = wid >> 1, wc = wid & 1;
  int l15 = lane & 15, l4 = lane >> 4;

  if (tid < 128) {
#pragma unroll
    for (int m = 0; m < 4; ++m)
      wx[tid][m] = b2f(Whi[tid * LDB + 256 + m]) + b2f(Wlo[tid * LDB + 256 + m]);
  } else if (tid < 192) {
    int nl = tid - 128;
    size_t o = ((size_t)(b * 512 + n0 + nl)) * LDB + 256;
#pragma unroll
    for (int m = 0; m < 4; ++m)
      xv[nl][m] = b2f(XShi[o + m]) + b2f(XSlo[o + m]);
  }

  f32x4 acc[4][2];
#pragma unroll
  for (int i = 0; i < 4; ++i)
#pragma unroll
    for (int j = 0; j < 2; ++j) acc[i][j] = (f32x4){0.f, 0.f, 0.f, 0.f};

  int aoff[2];
#pragma unroll
  for (int q = 0; q < 2; ++q) {
    int r = (wid * 2 + q) * 16 + (lane >> 2);
    aoff[q] = r * LDB + SLOT(lane & 3, r);
  }
  int rB = wid * 16 + (lane >> 2);
  size_t boff = ((size_t)(b * 512 + n0 + rB)) * LDB + SLOT(lane & 3, rB);

  int afr[4], bfr[2];
#pragma unroll
  for (int fm = 0; fm < 4; ++fm) {
    int ra = wr * 64 + fm * 16 + l15;
    afr[fm] = ra * 32 + SLOT(l4, ra);
  }
#pragma unroll
  for (int fn = 0; fn < 2; ++fn) {
    int rb = wc * 32 + fn * 16 + l15;
    bfr[fn] = rb * 32 + SLOT(l4, rb);
  }

#pragma unroll
  for (int q = 0; q < 2; ++q) {
    GLOAD(Whi + aoff[q], smem + (wid * 2 + q) * 512);
    GLOAD(Wlo + aoff[q], smem + 4096 + (wid * 2 + q) * 512);
  }
  GLOAD(XShi + boff, smem + 8192 + wid * 512);
  GLOAD(XSlo + boff, smem + 10240 + wid * 512);
  __syncthreads();

  int cur = 0;
#pragma unroll
  for (int t = 0; t < 8; ++t) {
    const short* cb = smem + cur * 12288;
    if (t < 7) {
      short* nb = smem + (cur ^ 1) * 12288;
      int k0 = (t + 1) * 32;
#pragma unroll
      for (int q = 0; q < 2; ++q) {
        GLOAD(Whi + aoff[q] + k0, nb + (wid * 2 + q) * 512);
        GLOAD(Wlo + aoff[q] + k0, nb + 4096 + (wid * 2 + q) * 512);
      }
      GLOAD(XShi + boff + k0, nb + 8192 + wid * 512);
      GLOAD(XSlo + boff + k0, nb + 10240 + wid * 512);
    }
    bf16x8 ah[4], al[4], bh[2], bl[2];
#pragma unroll
    for (int fm = 0; fm < 4; ++fm) {
      ah[fm] = *(const bf16x8*)&cb[afr[fm]];
      al[fm] = *(const bf16x8*)&cb[4096 + afr[fm]];
    }
#pragma unroll
    for (int fn = 0; fn < 2; ++fn) {
      bh[fn] = *(const bf16x8*)&cb[8192 + bfr[fn]];
      bl[fn] = *(const bf16x8*)&cb[10240 + bfr[fn]];
    }
#pragma unroll
    for (int fm = 0; fm < 4; ++fm)
#pragma unroll
      for (int fn = 0; fn < 2; ++fn) {
        acc[fm][fn] = __builtin_amdgcn_mfma_f32_16x16x32_bf16(ah[fm], bh[fn], acc[fm][fn], 0, 0, 0);
        acc[fm][fn] = __builtin_amdgcn_mfma_f32_16x16x32_bf16(al[fm], bh[fn], acc[fm][fn], 0, 0, 0);
        acc[fm][fn] = __builtin_amdgcn_mfma_f32_16x16x32_bf16(ah[fm], bl[fn], acc[fm][fn], 0, 0, 0);
      }
    __syncthreads();
    cur ^= 1;
  }

#pragma unroll
  for (int fm = 0; fm < 4; ++fm)
#pragma unroll
    for (int fn = 0; fn < 2; ++fn) {
      int nl = wc * 32 + fn * 16 + l15;
      int ng = n0 + nl;
      int jb = wr * 64 + fm * 16 + l4 * 4;
      if (wr == 0) {  // r-half: write r*h into X2 + XS m0
        short ph[4], pl[4];
#pragma unroll
        for (int rr = 0; rr < 4; ++rr) {
          int jg = jb + rr;
          float v = acc[fm][fn][rr] + wx[jg][0] * xv[nl][0] + wx[jg][1] * xv[nl][1]
                  + wx[jg][2] * xv[nl][2] + wx[jg][3] * xv[nl][3];
          float rg = 1.f / (1.f + expf(-(v + bias[jg])));
          size_t hrow = ((size_t)(b * 64 + jg)) * 512 + ng;
          float h = b2f(Xthi[hrow]) + b2f(Xtlo[hrow]);
          f2b2(rg * h, ph[rr], pl[rr]);
          X2hi[hrow] = ph[rr]; X2lo[hrow] = pl[rr];
        }
        size_t dst = ((size_t)(b * 512 + ng)) * LDB + jb;
        uint2 h2, l2;
        h2.x = (unsigned)(unsigned short)ph[0] | ((unsigned)(unsigned short)ph[1] << 16);
        h2.y = (unsigned)(unsigned short)ph[2] | ((unsigned)(unsigned short)ph[3] << 16);
        l2.x = (unsigned)(unsigned short)pl[0] | ((unsigned)(unsigned short)pl[1] << 16);
        l2.y = (unsigned)(unsigned short)pl[2] | ((unsigned)(unsigned short)pl[3] << 16);
        *(uint2*)(XShi + dst) = h2;
        *(uint2*)(XSlo + dst) = l2;
      } else {  // u-half
#pragma unroll
        for (int rr = 0; rr < 4; ++rr) {
          int jg = jb + rr;  // 64..127
          float v = acc[fm][fn][rr] + wx[jg][0] * xv[nl][0] + wx[jg][1] * xv[nl][1]
                  + wx[jg][2] * xv[nl][2] + wx[jg][3] * xv[nl][3];
          float u = 1.f / (1.f + expf(-(v + bias[jg])));
          Ut[((size_t)(b * 64 + (jg - 64))) * 512 + ng] = u;
        }
      }
    }
}

// ---------------- mix GEMM (c): K=256 + x-term; tanh + GRU + decoder out -------
__global__ __launch_bounds__(256) void k_mix_c(
    const short* __restrict__ Whi, const short* __restrict__ Wlo,   // [64,320]
    short* __restrict__ XShi, short* __restrict__ XSlo,             // read + m0/x write
    const float* __restrict__ bias,                                 // [64]
    const float* __restrict__ Ut,
    short* __restrict__ Xthi, short* __restrict__ Xtlo,             // h rows + x rows
    int dmode, const float* __restrict__ xsrc,
    const float* __restrict__ Wo, const float* __restrict__ bo,
    float* __restrict__ dout, int step) {
  __shared__ short smem[2 * 8192];  // per buf: Ah 2048 | Al 2048 | Bh 2048 | Bl 2048
  __shared__ float wx[64][4];
  __shared__ float xv[64][4];
  __shared__ float hls[64][66];
  int tid = threadIdx.x, lane = tid & 63, wid = tid >> 6;
  int n0 = blockIdx.x * 64, b = blockIdx.y;
  int wr = wid >> 1, wc = wid & 1;
  int l15 = lane & 15, l4 = lane >> 4;

  if (tid < 64) {
#pragma unroll
    for (int m = 0; m < 4; ++m)
      wx[tid][m] = b2f(Whi[tid * LDB + 256 + m]) + b2f(Wlo[tid * LDB + 256 + m]);
  } else if (tid < 128) {
    int nl = tid - 64;
    size_t o = ((size_t)(b * 512 + n0 + nl)) * LDB + 256;
#pragma unroll
    for (int m = 0; m < 4; ++m)
      xv[nl][m] = b2f(XShi[o + m]) + b2f(XSlo[o + m]);
  }

  f32x4 acc[2][2];
#pragma unroll
  for (int i = 0; i < 2; ++i)
#pragma unroll
    for (int j = 0; j < 2; ++j) acc[i][j] = (f32x4){0.f, 0.f, 0.f, 0.f};

  int rA = wid * 16 + (lane >> 2);
  int aoff = rA * LDB + SLOT(lane & 3, rA);
  size_t boff = ((size_t)(b * 512 + n0 + rA)) * LDB + SLOT(lane & 3, rA);

  int afr[2], bfr[2];
#pragma unroll
  for (int fm = 0; fm < 2; ++fm) {
    int ra = wr * 32 + fm * 16 + l15;
    afr[fm] = ra * 32 + SLOT(l4, ra);
  }
#pragma unroll
  for (int fn = 0; fn < 2; ++fn) {
    int rb = wc * 32 + fn * 16 + l15;
    bfr[fn] = rb * 32 + SLOT(l4, rb);
  }

  GLOAD(Whi + aoff, smem + wid * 512);
  GLOAD(Wlo + aoff, smem + 2048 + wid * 512);
  GLOAD(XShi + boff, smem + 4096 + wid * 512);
  GLOAD(XSlo + boff, smem + 6144 + wid * 512);
  __syncthreads();

  int cur = 0;
#pragma unroll
  for (int t = 0; t < 8; ++t) {
    const short* cb = smem + cur * 8192;
    if (t < 7) {
      short* nb = smem + (cur ^ 1) * 8192;
      int k0 = (t + 1) * 32;
      GLOAD(Whi + aoff + k0, nb + wid * 512);
      GLOAD(Wlo + aoff + k0, nb + 2048 + wid * 512);
      GLOAD(XShi + boff + k0, nb + 4096 + wid * 512);
      GLOAD(XSlo + boff + k0, nb + 6144 + wid * 512);
    }
    bf16x8 ah[2], al[2], bh[2], bl[2];
#pragma unroll
    for (int fm = 0; fm < 2; ++fm) {
      ah[fm] = *(const bf16x8*)&cb[afr[fm]];
      al[fm] = *(const bf16x8*)&cb[2048 + afr[fm]];
    }
#pragma unroll
    for (int fn = 0; fn < 2; ++fn) {
      bh[fn] = *(const bf16x8*)&cb[4096 + bfr[fn]];
      bl[fn] = *(const bf16x8*)&cb[6144 + bfr[fn]];
    }
#pragma unroll
    for (int fm = 0; fm < 2; ++fm)
#pragma unroll
      for (int fn = 0; fn < 2; ++fn) {
        acc[fm][fn] = __builtin_amdgcn_mfma_f32_16x16x32_bf16(ah[fm], bh[fn], acc[fm][fn], 0, 0, 0);
        acc[fm][fn] = __builtin_amdgcn_mfma_f32_16x16x32_bf16(al[fm], bh[fn], acc[fm][fn], 0, 0, 0);
        acc[fm][fn] = __builtin_amdgcn_mfma_f32_16x16x32_bf16(ah[fm], bl[fn], acc[fm][fn], 0, 0, 0);
      }
    __syncthreads();
    cur ^= 1;
  }

#pragma unroll
  for (int fm = 0; fm < 2; ++fm)
#pragma unroll
    for (int fn = 0; fn < 2; ++fn) {
      int nl = wc * 32 + fn * 16 + l15;
      int ng = n0 + nl;
      int jb = wr * 32 + fm * 16 + l4 * 4;
      short ph[4], pl[4];
#pragma unroll
      for (int rr = 0; rr < 4; ++rr) {
        int jg = jb + rr;
        float v = acc[fm][fn][rr] + wx[jg][0] * xv[nl][0] + wx[jg][1] * xv[nl][1]
                + wx[jg][2] * xv[nl][2] + wx[jg][3] * xv[nl][3];
        float cv = tanhf(v + bias[jg]);
        size_t hrow = ((size_t)(b * 64 + jg)) * 512 + ng;
        float u = Ut[hrow];
        float h = b2f(Xthi[hrow]) + b2f(Xtlo[hrow]);
        float hn = u * h + (1.f - u) * cv;
        f2b2(hn, ph[rr], pl[rr]);
        Xthi[hrow] = ph[rr]; Xtlo[hrow] = pl[rr];
        hls[jg][nl] = hn;
      }
      size_t dst = ((size_t)(b * 512 + ng)) * LDB + jb;
      uint2 h2, l2;
      h2.x = (unsigned)(unsigned short)ph[0] | ((unsigned)(unsigned short)ph[1] << 16);
      h2.y = (unsigned)(unsigned short)ph[2] | ((unsigned)(unsigned short)ph[3] << 16);
      l2.x = (unsigned)(unsigned short)pl[0] | ((unsigned)(unsigned short)pl[1] << 16);
      l2.y = (unsigned)(unsigned short)pl[2] | ((unsigned)(unsigned short)pl[3] << 16);
      *(uint2*)(XShi + dst) = h2;
      *(uint2*)(XSlo + dst) = l2;
    }

  __syncthreads();
  if (dmode) {
    if (tid < 64) {
      int ng = n0 + tid;
      float s = bo[0];
#pragma unroll
      for (int j = 0; j < 64; ++j) s += hls[j][tid] * Wo[j];
      dout[((size_t)b * 12 + step) * 512 + ng] = s;
      short hh, ll; f2b2(s, hh, ll);
      size_t o = ((size_t)(2048 + b)) * 512 + ng;
      Xthi[o] = hh; Xtlo[o] = ll;
      size_t o2 = ((size_t)(b * 512 + ng)) * LDB + 256;
      XShi[o2] = hh; XSlo[o2] = ll;
    }
  } else {
    if (tid < 64) {
      int ng = n0 + tid;
      float x = xsrc ? xsrc[(size_t)b * 6144 + ng] : 0.f;
      short hh, ll; f2b2(x, hh, ll);
      size_t o = ((size_t)(2048 + b)) * 512 + ng;
      Xthi[o] = hh; Xtlo[o] = ll;
      size_t o2 = ((size_t)(b * 512 + ng)) * LDB + 256;
      XShi[o2] = hh; XSlo[o2] = ll;
    }
  }
}

extern "C" void kernel_launch(void* const* d_in, const int* in_sizes, int n_in,
                              void* d_out, int out_size, void* d_ws, size_t ws_size,
                              hipStream_t stream) {
  const float* inputs = (const float*)d_in[0];
  const float* graph  = (const float*)d_in[1];
  const float* eWru = (const float*)d_in[2];
  const float* ebru = (const float*)d_in[3];
  const float* eWc  = (const float*)d_in[4];
  const float* ebc  = (const float*)d_in[5];
  const float* dWru = (const float*)d_in[6];
  const float* dbru = (const float*)d_in[7];
  const float* dWc  = (const float*)d_in[8];
  const float* dbc  = (const float*)d_in[9];
  const float* dWo  = (const float*)d_in[10];
  const float* dbo  = (const float*)d_in[11];
  float* out = (float*)d_out;

  char* w = (char*)d_ws;
  auto carve = [&](size_t bytes) {
    char* p = w; w += (bytes + 255) & ~(size_t)255; return p;
  };
  short* Tshi = (short*)carve((size_t)1536 * 512 * 2);
  short* Tslo = (short*)carve((size_t)1536 * 512 * 2);
  short* Xthi = (short*)carve((size_t)2176 * 512 * 2);
  short* Xtlo = (short*)carve((size_t)2176 * 512 * 2);
  short* X2hi = (short*)carve((size_t)2048 * 512 * 2);
  short* X2lo = (short*)carve((size_t)2048 * 512 * 2);
  short* XShi = (short*)carve((size_t)16384 * LDB * 2);
  short* XSlo = (short*)carve((size_t)16384 * LDB * 2);
  float* Ut   = (float*)carve((size_t)2048 * 512 * 4);
  float* TMP  = (float*)carve((size_t)512 * 512 * 4);
  float* TMP2 = (float*)carve((size_t)512 * 512 * 4);
  short* Bthi = (short*)carve((size_t)512 * 512 * 2);
  short* Btlo = (short*)carve((size_t)512 * 512 * 2);
  short* eWruHi = (short*)carve((size_t)128 * LDB * 2);
  short* eWruLo = (short*)carve((size_t)128 * LDB * 2);
  short* eWcHi  = (short*)carve((size_t)64 * LDB * 2);
  short* eWcLo  = (short*)carve((size_t)64 * LDB * 2);
  short* dWruHi = (short*)carve((size_t)128 * LDB * 2);
  short* dWruLo = (short*)carve((size_t)128 * LDB * 2);
  short* dWcHi  = (short*)carve((size_t)64 * LDB * 2);
  short* dWcLo  = (short*)carve((size_t)64 * LDB * 2);
  if ((size_t)(w - (char*)d_ws) > ws_size) return;

  dim3 blk(256);
  // zero Xt (h0 + x pads) and m0 slots of XS (h0)
  k_zeroxt<<<545, blk, 0, stream>>>((uint4*)Xthi, (uint4*)Xtlo, 139264);
  k_zerom0<<<512, blk, 0, stream>>>(XShi, XSlo);

  // T-stack [T1;T2;T3]
  k_prepT<<<1024, blk, 0, stream>>>(graph, Tshi, Tslo, 512 * 512);
  t512<<<dim3(16, 16), blk, 0, stream>>>(graph, Bthi, Btlo);
  gemm_bt<<<dim3(8, 4), blk, 0, stream>>>(Tshi, Tslo, Bthi, Btlo, TMP, 512,
                                          nullptr, nullptr, 0);
  k_cheb2b<<<1024, blk, 0, stream>>>(TMP, Tshi + 512 * 512, Tslo + 512 * 512);
  t512<<<dim3(16, 16), blk, 0, stream>>>(TMP, Bthi, Btlo);
  gemm_bt<<<dim3(8, 4), blk, 0, stream>>>(Tshi, Tslo, Bthi, Btlo, TMP2, 512,
                                          nullptr, nullptr, 0);
  k_cheb3b<<<1024, blk, 0, stream>>>(TMP2, graph, Tshi + 1024 * 512, Tslo + 1024 * 512);

  k_prepW<<<160, blk, 0, stream>>>(eWru, eWruHi, eWruLo, 128);
  k_prepW<<<80,  blk, 0, stream>>>(eWc,  eWcHi,  eWcLo,  64);
  k_prepW<<<160, blk, 0, stream>>>(dWru, dWruHi, dWruLo, 128);
  k_prepW<<<80,  blk, 0, stream>>>(dWc,  dWcHi,  dWcLo,  64);
  k_setx0<<<64, blk, 0, stream>>>(inputs, Xthi, Xtlo, XShi, XSlo);

  dim3 d1Grid(24, 17);  // h-rows + x-block
  dim3 d2Grid(24, 16);  // h-rows only (T*x slots persist)
  dim3 mGrid(8, 32);

  for (int t = 0; t < 24; ++t) {
    bool enc = t < 12;
    const short* wruh = enc ? eWruHi : dWruHi;
    const short* wrul = enc ? eWruLo : dWruLo;
    const short* wch  = enc ? eWcHi  : dWcHi;
    const short* wcl  = enc ? eWcLo  : dWcLo;
    const float* bru  = enc ? ebru : dbru;
    const float* bc   = enc ? ebc  : dbc;

    gemm_bt<<<d1Grid, blk, 0, stream>>>(Xthi, Xtlo, Tshi, Tslo,
                                        nullptr, 0, XShi, XSlo, 1);
    k_mix_ru<<<mGrid, blk, 0, stream>>>(wruh, wrul, XShi, XSlo, bru,
                                        Xthi, Xtlo, X2hi, X2lo, Ut);
    gemm_bt<<<d2Grid, blk, 0, stream>>>(X2hi, X2lo, Tshi, Tslo,
                                        nullptr, 0, XShi, XSlo, 1);
    if (enc) {
      const float* xs = (t < 11) ? inputs + (size_t)(t + 1) * 512 : nullptr;
      k_mix_c<<<mGrid, blk, 0, stream>>>(wch, wcl, XShi, XSlo, bc, Ut,
                                         Xthi, Xtlo, 0, xs,
                                         nullptr, nullptr, nullptr, 0);
    } else {
      k_mix_c<<<mGrid, blk, 0, stream>>>(wch, wcl, XShi, XSlo, bc, Ut,
                                         Xthi, Xtlo, 1, nullptr,
                                         dWo, dbo, out, t - 12);
    }
  }
}

// Round 10
// 1552.476 us; speedup vs baseline: 1.5221x; 1.0301x over previous
//
#include <hip/hip_runtime.h>
#include <hip/hip_bf16.h>
#include <math.h>

#define LDB 320   // XSmix row: k = m*64+dh (m=0 id, 1..3 = T_m), 256..259 = x,Tx; pad->320
// LDS slot swizzle: period-8 over rows -> 2-way bank aliasing (free) on ds_read_b128.
// MUST be applied identically on the global-source side and the frag-read side.
#define SLOT(c, r) (((c) ^ (((r) >> 1) & 3)) * 8)

typedef __attribute__((ext_vector_type(8))) short bf16x8;
typedef __attribute__((ext_vector_type(4))) float f32x4;

__device__ __forceinline__ float b2f(short s) {
  unsigned u = ((unsigned)(unsigned short)s) << 16;
  return __uint_as_float(u);
}
__device__ __forceinline__ short f2bh(float x) {
  __hip_bfloat16 h = __float2bfloat16(x);
  return *(short*)&h;
}
__device__ __forceinline__ void f2b2(float x, short& hi, short& lo) {
  hi = f2bh(x);
  lo = f2bh(x - b2f(hi));
}

#define GLOAD(src, dst) \
  __builtin_amdgcn_global_load_lds( \
      (const __attribute__((address_space(1))) void*)(src), \
      (__attribute__((address_space(3))) void*)(dst), 16, 0, 0)

// ---------------- utility kernels ----------------
__global__ void k_zeroxt(uint4* a, uint4* b, int n) {
  int i = blockIdx.x * 256 + threadIdx.x;
  if (i < n) { a[i] = (uint4){0,0,0,0}; b[i] = (uint4){0,0,0,0}; }
}

// zero only the m0 slots (k 0..63) of every XS row (h0 = 0); pads never read
__global__ void k_zerom0(short* __restrict__ XShi, short* __restrict__ XSlo) {
  int i = blockIdx.x * 256 + threadIdx.x;
  if (i >= 16384 * 8) return;
  int row = i >> 3, ch = i & 7;
  size_t o = (size_t)row * LDB + ch * 8;
  *(uint4*)(XShi + o) = (uint4){0,0,0,0};
  *(uint4*)(XSlo + o) = (uint4){0,0,0,0};
}

__global__ void k_prepT(const float* __restrict__ S, short* __restrict__ hi,
                        short* __restrict__ lo, int n) {
  int i = blockIdx.x * 256 + threadIdx.x;
  if (i >= n) return;
  short h, l; f2b2(S[i], h, l);
  hi[i] = h; lo[i] = l;
}

__global__ void k_cheb2b(float* __restrict__ AA, short* __restrict__ hi,
                         short* __restrict__ lo) {
  int i = blockIdx.x * 256 + threadIdx.x;
  if (i >= 512 * 512) return;
  int r = i >> 9, c = i & 511;
  float v = 2.f * AA[i] - (r == c ? 1.f : 0.f);
  AA[i] = v;
  short h, l; f2b2(v, h, l);
  hi[i] = h; lo[i] = l;
}

__global__ void k_cheb3b(const float* __restrict__ AT2, const float* __restrict__ A,
                         short* __restrict__ hi, short* __restrict__ lo) {
  int i = blockIdx.x * 256 + threadIdx.x;
  if (i >= 512 * 512) return;
  float v = 2.f * AT2[i] - A[i];
  short h, l; f2b2(v, h, l);
  hi[i] = h; lo[i] = l;
}

// transpose + split a 512x512 f32 matrix -> [c][r] bf16 hi/lo
__global__ __launch_bounds__(256) void t512(const float* __restrict__ in,
                                            short* __restrict__ ohi,
                                            short* __restrict__ olo) {
  __shared__ float t[32][33];
  int c0 = blockIdx.x * 32, r0 = blockIdx.y * 32;
  int tid = threadIdx.x;
  int cc = tid & 31, rr = tid >> 5;
#pragma unroll
  for (int p = 0; p < 4; ++p)
    t[rr + p * 8][cc] = in[(size_t)(r0 + rr + p * 8) * 512 + c0 + cc];
  __syncthreads();
#pragma unroll
  for (int p = 0; p < 4; ++p) {
    int c = rr + p * 8, r = cc;
    short h, l; f2b2(t[r][c], h, l);
    size_t o = (size_t)(c0 + c) * 512 + r0 + r;
    ohi[o] = h; olo[o] = l;
  }
}

// Wt[j][k]: k<256 -> W[(1+(k&63))*4 + (k>>6)][j]; k 256..259 -> W[k-256][j]; else 0
__global__ void k_prepW(const float* __restrict__ W, short* __restrict__ hi,
                        short* __restrict__ lo, int J) {
  int i = blockIdx.x * 256 + threadIdx.x;
  if (i >= J * LDB) return;
  int j = i / LDB, k = i - j * LDB;
  float v = 0.f;
  if (k < 256) {
    int m = k >> 6, dh = k & 63;
    v = W[(size_t)((1 + dh) * 4 + m) * J + j];
  } else if (k < 260) {
    v = W[(size_t)(k - 256) * J + j];
  }
  short h, l; f2b2(v, h, l);
  hi[i] = h; lo[i] = l;
}

// x(t=0) -> Xt x-rows (2048+b) and XS k=256
__global__ void k_setx0(const float* __restrict__ inp, short* __restrict__ Xthi,
                        short* __restrict__ Xtlo, short* __restrict__ XShi,
                        short* __restrict__ XSlo) {
  int i = blockIdx.x * 256 + threadIdx.x;
  if (i >= 32 * 512) return;
  int b = i >> 9, n = i & 511;
  float x = inp[(size_t)b * 6144 + n];
  short h, l; f2b2(x, h, l);
  size_t o = ((size_t)(2048 + b)) * 512 + n;
  Xthi[o] = h; Xtlo[o] = l;
  size_t o2 = ((size_t)(b * 512 + n)) * LDB + 256;
  XShi[o2] = h; XSlo[o2] = l;
}

// ---------------- split GEMM, BM=128 BN=64 BK=32, 2-phase dbuf ----------------
// C = (Ahi+Alo) @ (Bhi+Blo)^T ; A rows [*,512], B rows [*,512].
// mode 0: C f32 [ldc].  mode 1: XSmix epilogue (h-rows m=1..3; x-block -> 257+mq).
// Bijective XCD-chunk swizzle (all grids divisible by 8) for L2 locality.
__global__ __launch_bounds__(256) void gemm_bt(
    const short* __restrict__ Ahi, const short* __restrict__ Alo,
    const short* __restrict__ Bhi, const short* __restrict__ Blo,
    float* __restrict__ Cf, int ldc,
    short* __restrict__ XShi, short* __restrict__ XSlo, int mode) {
  __shared__ short smem[2 * 12288];  // per buf: Ah 4096 | Al 4096 | Bh 2048 | Bl 2048
  int tid = threadIdx.x, lane = tid & 63, wid = tid >> 6;
  int nwg = gridDim.x * gridDim.y;
  int lin = blockIdx.y * gridDim.x + blockIdx.x;
  int swz = (lin & 7) * (nwg >> 3) + (lin >> 3);
  int bx = swz % gridDim.x, by = swz / gridDim.x;
  int r0 = by * 128, c0 = bx * 64;
  int wr = wid >> 1, wc = wid & 1;
  int l15 = lane & 15, l4 = lane >> 4;

  f32x4 acc[4][2];
#pragma unroll
  for (int i = 0; i < 4; ++i)
#pragma unroll
    for (int j = 0; j < 2; ++j) acc[i][j] = (f32x4){0.f, 0.f, 0.f, 0.f};

  int aoff[2];
#pragma unroll
  for (int q = 0; q < 2; ++q) {
    int r = (wid * 2 + q) * 16 + (lane >> 2);
    aoff[q] = (r0 + r) * 512 + SLOT(lane & 3, r);
  }
  int rB = wid * 16 + (lane >> 2);
  int boff = (c0 + rB) * 512 + SLOT(lane & 3, rB);

  int afr[4], bfr[2];
#pragma unroll
  for (int fm = 0; fm < 4; ++fm) {
    int ra = wr * 64 + fm * 16 + l15;
    afr[fm] = ra * 32 + SLOT(l4, ra);
  }
#pragma unroll
  for (int fn = 0; fn < 2; ++fn) {
    int rb = wc * 32 + fn * 16 + l15;
    bfr[fn] = rb * 32 + SLOT(l4, rb);
  }

#pragma unroll
  for (int q = 0; q < 2; ++q) {
    GLOAD(Ahi + aoff[q], smem + (wid * 2 + q) * 512);
    GLOAD(Alo + aoff[q], smem + 4096 + (wid * 2 + q) * 512);
  }
  GLOAD(Bhi + boff, smem + 8192 + wid * 512);
  GLOAD(Blo + boff, smem + 10240 + wid * 512);
  __syncthreads();

  int cur = 0;
#pragma unroll
  for (int t = 0; t < 16; ++t) {
    const short* cb = smem + cur * 12288;
    if (t < 15) {
      short* nb = smem + (cur ^ 1) * 12288;
      int k0 = (t + 1) * 32;
#pragma unroll
      for (int q = 0; q < 2; ++q) {
        GLOAD(Ahi + aoff[q] + k0, nb + (wid * 2 + q) * 512);
        GLOAD(Alo + aoff[q] + k0, nb + 4096 + (wid * 2 + q) * 512);
      }
      GLOAD(Bhi + boff + k0, nb + 8192 + wid * 512);
      GLOAD(Blo + boff + k0, nb + 10240 + wid * 512);
    }
    bf16x8 ah[4], al[4], bh[2], bl[2];
#pragma unroll
    for (int fm = 0; fm < 4; ++fm) {
      ah[fm] = *(const bf16x8*)&cb[afr[fm]];
      al[fm] = *(const bf16x8*)&cb[4096 + afr[fm]];
    }
#pragma unroll
    for (int fn = 0; fn < 2; ++fn) {
      bh[fn] = *(const bf16x8*)&cb[8192 + bfr[fn]];
      bl[fn] = *(const bf16x8*)&cb[10240 + bfr[fn]];
    }
#pragma unroll
    for (int fm = 0; fm < 4; ++fm)
#pragma unroll
      for (int fn = 0; fn < 2; ++fn) {
        acc[fm][fn] = __builtin_amdgcn_mfma_f32_16x16x32_bf16(ah[fm], bh[fn], acc[fm][fn], 0, 0, 0);
        acc[fm][fn] = __builtin_amdgcn_mfma_f32_16x16x32_bf16(al[fm], bh[fn], acc[fm][fn], 0, 0, 0);
        acc[fm][fn] = __builtin_amdgcn_mfma_f32_16x16x32_bf16(ah[fm], bl[fn], acc[fm][fn], 0, 0, 0);
      }
    __syncthreads();
    cur ^= 1;
  }

  if (mode == 0) {
#pragma unroll
    for (int fm = 0; fm < 4; ++fm)
#pragma unroll
      for (int fn = 0; fn < 2; ++fn) {
        int row = r0 + wr * 64 + fm * 16 + l4 * 4;
        int col = c0 + wc * 32 + fn * 16 + l15;
#pragma unroll
        for (int rr = 0; rr < 4; ++rr)
          Cf[(size_t)(row + rr) * ldc + col] = acc[fm][fn][rr];
      }
  } else {
    // pack hi|lo into u32, LDS-transpose, then coalesced 8-B global stores.
    unsigned* uT = (unsigned*)smem;  // [64 n][140 r] packed hi|lo
#pragma unroll
    for (int fm = 0; fm < 4; ++fm)
#pragma unroll
      for (int fn = 0; fn < 2; ++fn) {
        int nl = wc * 32 + fn * 16 + l15;
        int rbase = wr * 64 + fm * 16 + l4 * 4;
        unsigned pk[4];
#pragma unroll
        for (int rr = 0; rr < 4; ++rr) {
          short h, l; f2b2(acc[fm][fn][rr], h, l);
          pk[rr] = (unsigned)(unsigned short)h | ((unsigned)(unsigned short)l << 16);
        }
        uint2 w0; w0.x = pk[0]; w0.y = pk[1];
        uint2 w1; w1.x = pk[2]; w1.y = pk[3];
        *(uint2*)&uT[nl * 140 + rbase] = w0;
        *(uint2*)&uT[nl * 140 + rbase + 2] = w1;
      }
    __syncthreads();
    int mq = bx >> 3;        // 0..2 -> T_{mq+1}
    int n0s = (bx & 7) * 64;
    if (r0 < 2048) {
      int b0 = r0 >> 6;
#pragma unroll
      for (int l = 0; l < 8; ++l) {
        int e = tid + l * 256;
        int ch = e & 15, bg = (e >> 4) & 1, nl = e >> 5;
        uint4 v = *(const uint4*)&uT[nl * 140 + bg * 64 + ch * 4];
        uint2 hi2, lo2;
        hi2.x = (v.x & 0xffffu) | (v.y << 16);
        hi2.y = (v.z & 0xffffu) | (v.w << 16);
        lo2.x = (v.x >> 16) | (v.y & 0xffff0000u);
        lo2.y = (v.z >> 16) | (v.w & 0xffff0000u);
        size_t dst = ((size_t)((b0 + bg) * 512 + n0s + nl)) * LDB + (mq + 1) * 64 + ch * 4;
        *(uint2*)(XShi + dst) = hi2;
        *(uint2*)(XSlo + dst) = lo2;
      }
    } else {
#pragma unroll
      for (int l = 0; l < 8; ++l) {
        int e = tid + l * 256;
        int nl = e & 63, b = e >> 6;
        unsigned v = uT[nl * 140 + b];
        size_t dst = ((size_t)(b * 512 + n0s + nl)) * LDB + 257 + mq;
        XShi[dst] = (short)(v & 0xffffu);
        XSlo[dst] = (short)(v >> 16);
      }
    }
  }
}

// ---------------- mix GEMM (ru): 64j x 64n per block (z = j-half), K=256 -------
// z=0: r gate (j 0..63) -> r*h into X2 + XS m0.  z=1: u gate (j 64..127) -> Ut.
// 512 blocks -> 2 blocks/CU for latency overlap.
__global__ __launch_bounds__(256) void k_mix_ru(
    const short* __restrict__ Whi, const short* __restrict__ Wlo,   // [128,320]
    short* __restrict__ XShi, short* __restrict__ XSlo,             // read + m0 write
    const float* __restrict__ bias,                                 // [128]
    const short* __restrict__ Xthi, const short* __restrict__ Xtlo, // h-old rows
    short* __restrict__ X2hi, short* __restrict__ X2lo,             // r*h rows
    float* __restrict__ Ut) {
  __shared__ short smem[2 * 8192];  // per buf: Wh 2048 | Wl 2048 | XSh 2048 | XSl 2048
  __shared__ float wx[64][4];
  __shared__ float xv[64][4];
  int tid = threadIdx.x, lane = tid & 63, wid = tid >> 6;
  int n0 = blockIdx.x * 64, b = blockIdx.y, z = blockIdx.z;
  int wr = wid >> 1, wc = wid & 1;
  int l15 = lane & 15, l4 = lane >> 4;
  const short* Wh = Whi + (size_t)z * 64 * LDB;
  const short* Wl = Wlo + (size_t)z * 64 * LDB;

  if (tid < 64) {
#pragma unroll
    for (int m = 0; m < 4; ++m)
      wx[tid][m] = b2f(Wh[tid * LDB + 256 + m]) + b2f(Wl[tid * LDB + 256 + m]);
  } else if (tid < 128) {
    int nl = tid - 64;
    size_t o = ((size_t)(b * 512 + n0 + nl)) * LDB + 256;
#pragma unroll
    for (int m = 0; m < 4; ++m)
      xv[nl][m] = b2f(XShi[o + m]) + b2f(XSlo[o + m]);
  }

  f32x4 acc[2][2];
#pragma unroll
  for (int i = 0; i < 2; ++i)
#pragma unroll
    for (int j = 0; j < 2; ++j) acc[i][j] = (f32x4){0.f, 0.f, 0.f, 0.f};

  int rS = wid * 16 + (lane >> 2);
  int aoff = rS * LDB + SLOT(lane & 3, rS);
  size_t boff = ((size_t)(b * 512 + n0 + rS)) * LDB + SLOT(lane & 3, rS);

  int afr[2], bfr[2];
#pragma unroll
  for (int fm = 0; fm < 2; ++fm) {
    int ra = wr * 32 + fm * 16 + l15;
    afr[fm] = ra * 32 + SLOT(l4, ra);
  }
#pragma unroll
  for (int fn = 0; fn < 2; ++fn) {
    int rb = wc * 32 + fn * 16 + l15;
    bfr[fn] = rb * 32 + SLOT(l4, rb);
  }

  GLOAD(Wh + aoff, smem + wid * 512);
  GLOAD(Wl + aoff, smem + 2048 + wid * 512);
  GLOAD(XShi + boff, smem + 4096 + wid * 512);
  GLOAD(XSlo + boff, smem + 6144 + wid * 512);
  __syncthreads();

  int cur = 0;
#pragma unroll
  for (int t = 0; t < 8; ++t) {
    const short* cb = smem + cur * 8192;
    if (t < 7) {
      short* nb = smem + (cur ^ 1) * 8192;
      int k0 = (t + 1) * 32;
      GLOAD(Wh + aoff + k0, nb + wid * 512);
      GLOAD(Wl + aoff + k0, nb + 2048 + wid * 512);
      GLOAD(XShi + boff + k0, nb + 4096 + wid * 512);
      GLOAD(XSlo + boff + k0, nb + 6144 + wid * 512);
    }
    bf16x8 ah[2], al[2], bh[2], bl[2];
#pragma unroll
    for (int fm = 0; fm < 2; ++fm) {
      ah[fm] = *(const bf16x8*)&cb[afr[fm]];
      al[fm] = *(const bf16x8*)&cb[2048 + afr[fm]];
    }
#pragma unroll
    for (int fn = 0; fn < 2; ++fn) {
      bh[fn] = *(const bf16x8*)&cb[4096 + bfr[fn]];
      bl[fn] = *(const bf16x8*)&cb[6144 + bfr[fn]];
    }
#pragma unroll
    for (int fm = 0; fm < 2; ++fm)
#pragma unroll
      for (int fn = 0; fn < 2; ++fn) {
        acc[fm][fn] = __builtin_amdgcn_mfma_f32_16x16x32_bf16(ah[fm], bh[fn], acc[fm][fn], 0, 0, 0);
        acc[fm][fn] = __builtin_amdgcn_mfma_f32_16x16x32_bf16(al[fm], bh[fn], acc[fm][fn], 0, 0, 0);
        acc[fm][fn] = __builtin_amdgcn_mfma_f32_16x16x32_bf16(ah[fm], bl[fn], acc[fm][fn], 0, 0, 0);
      }
    __syncthreads();
    cur ^= 1;
  }

#pragma unroll
  for (int fm = 0; fm < 2; ++fm)
#pragma unroll
    for (int fn = 0; fn < 2; ++fn) {
      int nl = wc * 32 + fn * 16 + l15;
      int ng = n0 + nl;
      int jb = wr * 32 + fm * 16 + l4 * 4;   // local j 0..63
      if (z == 0) {  // r-half: write r*h into X2 + XS m0
        short ph[4], pl[4];
#pragma unroll
        for (int rr = 0; rr < 4; ++rr) {
          int jg = jb + rr;
          float v = acc[fm][fn][rr] + wx[jg][0] * xv[nl][0] + wx[jg][1] * xv[nl][1]
                  + wx[jg][2] * xv[nl][2] + wx[jg][3] * xv[nl][3];
          float rg = 1.f / (1.f + expf(-(v + bias[jg])));
          size_t hrow = ((size_t)(b * 64 + jg)) * 512 + ng;
          float h = b2f(Xthi[hrow]) + b2f(Xtlo[hrow]);
          f2b2(rg * h, ph[rr], pl[rr]);
          X2hi[hrow] = ph[rr]; X2lo[hrow] = pl[rr];
        }
        size_t dst = ((size_t)(b * 512 + ng)) * LDB + jb;
        uint2 h2, l2;
        h2.x = (unsigned)(unsigned short)ph[0] | ((unsigned)(unsigned short)ph[1] << 16);
        h2.y = (unsigned)(unsigned short)ph[2] | ((unsigned)(unsigned short)ph[3] << 16);
        l2.x = (unsigned)(unsigned short)pl[0] | ((unsigned)(unsigned short)pl[1] << 16);
        l2.y = (unsigned)(unsigned short)pl[2] | ((unsigned)(unsigned short)pl[3] << 16);
        *(uint2*)(XShi + dst) = h2;
        *(uint2*)(XSlo + dst) = l2;
      } else {  // u-half
#pragma unroll
        for (int rr = 0; rr < 4; ++rr) {
          int jg = jb + rr;
          float v = acc[fm][fn][rr] + wx[jg][0] * xv[nl][0] + wx[jg][1] * xv[nl][1]
                  + wx[jg][2] * xv[nl][2] + wx[jg][3] * xv[nl][3];
          float u = 1.f / (1.f + expf(-(v + bias[64 + jg])));
          Ut[((size_t)(b * 64 + jg)) * 512 + ng] = u;
        }
      }
    }
}

// ---------------- mix GEMM (c): K=256 + x-term; tanh + GRU + decoder out -------
__global__ __launch_bounds__(256) void k_mix_c(
    const short* __restrict__ Whi, const short* __restrict__ Wlo,   // [64,320]
    short* __restrict__ XShi, short* __restrict__ XSlo,             // read + m0/x write
    const float* __restrict__ bias,                                 // [64]
    const float* __restrict__ Ut,
    short* __restrict__ Xthi, short* __restrict__ Xtlo,             // h rows + x rows
    int dmode, const float* __restrict__ xsrc,
    const float* __restrict__ Wo, const float* __restrict__ bo,
    float* __restrict__ dout, int step) {
  __shared__ short smem[2 * 8192];  // per buf: Ah 2048 | Al 2048 | Bh 2048 | Bl 2048
  __shared__ float wx[64][4];
  __shared__ float xv[64][4];
  __shared__ float hls[64][66];
  int tid = threadIdx.x, lane = tid & 63, wid = tid >> 6;
  int n0 = blockIdx.x * 64, b = blockIdx.y;
  int wr = wid >> 1, wc = wid & 1;
  int l15 = lane & 15, l4 = lane >> 4;

  if (tid < 64) {
#pragma unroll
    for (int m = 0; m < 4; ++m)
      wx[tid][m] = b2f(Whi[tid * LDB + 256 + m]) + b2f(Wlo[tid * LDB + 256 + m]);
  } else if (tid < 128) {
    int nl = tid - 64;
    size_t o = ((size_t)(b * 512 + n0 + nl)) * LDB + 256;
#pragma unroll
    for (int m = 0; m < 4; ++m)
      xv[nl][m] = b2f(XShi[o + m]) + b2f(XSlo[o + m]);
  }

  f32x4 acc[2][2];
#pragma unroll
  for (int i = 0; i < 2; ++i)
#pragma unroll
    for (int j = 0; j < 2; ++j) acc[i][j] = (f32x4){0.f, 0.f, 0.f, 0.f};

  int rA = wid * 16 + (lane >> 2);
  int aoff = rA * LDB + SLOT(lane & 3, rA);
  size_t boff = ((size_t)(b * 512 + n0 + rA)) * LDB + SLOT(lane & 3, rA);

  int afr[2], bfr[2];
#pragma unroll
  for (int fm = 0; fm < 2; ++fm) {
    int ra = wr * 32 + fm * 16 + l15;
    afr[fm] = ra * 32 + SLOT(l4, ra);
  }
#pragma unroll
  for (int fn = 0; fn < 2; ++fn) {
    int rb = wc * 32 + fn * 16 + l15;
    bfr[fn] = rb * 32 + SLOT(l4, rb);
  }

  GLOAD(Whi + aoff, smem + wid * 512);
  GLOAD(Wlo + aoff, smem + 2048 + wid * 512);
  GLOAD(XShi + boff, smem + 4096 + wid * 512);
  GLOAD(XSlo + boff, smem + 6144 + wid * 512);
  __syncthreads();

  int cur = 0;
#pragma unroll
  for (int t = 0; t < 8; ++t) {
    const short* cb = smem + cur * 8192;
    if (t < 7) {
      short* nb = smem + (cur ^ 1) * 8192;
      int k0 = (t + 1) * 32;
      GLOAD(Whi + aoff + k0, nb + wid * 512);
      GLOAD(Wlo + aoff + k0, nb + 2048 + wid * 512);
      GLOAD(XShi + boff + k0, nb + 4096 + wid * 512);
      GLOAD(XSlo + boff + k0, nb + 6144 + wid * 512);
    }
    bf16x8 ah[2], al[2], bh[2], bl[2];
#pragma unroll
    for (int fm = 0; fm < 2; ++fm) {
      ah[fm] = *(const bf16x8*)&cb[afr[fm]];
      al[fm] = *(const bf16x8*)&cb[2048 + afr[fm]];
    }
#pragma unroll
    for (int fn = 0; fn < 2; ++fn) {
      bh[fn] = *(const bf16x8*)&cb[4096 + bfr[fn]];
      bl[fn] = *(const bf16x8*)&cb[6144 + bfr[fn]];
    }
#pragma unroll
    for (int fm = 0; fm < 2; ++fm)
#pragma unroll
      for (int fn = 0; fn < 2; ++fn) {
        acc[fm][fn] = __builtin_amdgcn_mfma_f32_16x16x32_bf16(ah[fm], bh[fn], acc[fm][fn], 0, 0, 0);
        acc[fm][fn] = __builtin_amdgcn_mfma_f32_16x16x32_bf16(al[fm], bh[fn], acc[fm][fn], 0, 0, 0);
        acc[fm][fn] = __builtin_amdgcn_mfma_f32_16x16x32_bf16(ah[fm], bl[fn], acc[fm][fn], 0, 0, 0);
      }
    __syncthreads();
    cur ^= 1;
  }

#pragma unroll
  for (int fm = 0; fm < 2; ++fm)
#pragma unroll
    for (int fn = 0; fn < 2; ++fn) {
      int nl = wc * 32 + fn * 16 + l15;
      int ng = n0 + nl;
      int jb = wr * 32 + fm * 16 + l4 * 4;
      short ph[4], pl[4];
#pragma unroll
      for (int rr = 0; rr < 4; ++rr) {
        int jg = jb + rr;
        float v = acc[fm][fn][rr] + wx[jg][0] * xv[nl][0] + wx[jg][1] * xv[nl][1]
                + wx[jg][2] * xv[nl][2] + wx[jg][3] * xv[nl][3];
        float cv = tanhf(v + bias[jg]);
        size_t hrow = ((size_t)(b * 64 + jg)) * 512 + ng;
        float u = Ut[hrow];
        float h = b2f(Xthi[hrow]) + b2f(Xtlo[hrow]);
        float hn = u * h + (1.f - u) * cv;
        f2b2(hn, ph[rr], pl[rr]);
        Xthi[hrow] = ph[rr]; Xtlo[hrow] = pl[rr];
        hls[jg][nl] = hn;
      }
      size_t dst = ((size_t)(b * 512 + ng)) * LDB + jb;
      uint2 h2, l2;
      h2.x = (unsigned)(unsigned short)ph[0] | ((unsigned)(unsigned short)ph[1] << 16);
      h2.y = (unsigned)(unsigned short)ph[2] | ((unsigned)(unsigned short)ph[3] << 16);
      l2.x = (unsigned)(unsigned short)pl[0] | ((unsigned)(unsigned short)pl[1] << 16);
      l2.y = (unsigned)(unsigned short)pl[2] | ((unsigned)(unsigned short)pl[3] << 16);
      *(uint2*)(XShi + dst) = h2;
      *(uint2*)(XSlo + dst) = l2;
    }

  __syncthreads();
  if (dmode) {
    if (tid < 64) {
      int ng = n0 + tid;
      float s = bo[0];
#pragma unroll
      for (int j = 0; j < 64; ++j) s += hls[j][tid] * Wo[j];
      dout[((size_t)b * 12 + step) * 512 + ng] = s;
      short hh, ll; f2b2(s, hh, ll);
      size_t o = ((size_t)(2048 + b)) * 512 + ng;
      Xthi[o] = hh; Xtlo[o] = ll;
      size_t o2 = ((size_t)(b * 512 + ng)) * LDB + 256;
      XShi[o2] = hh; XSlo[o2] = ll;
    }
  } else {
    if (tid < 64) {
      int ng = n0 + tid;
      float x = xsrc ? xsrc[(size_t)b * 6144 + ng] : 0.f;
      short hh, ll; f2b2(x, hh, ll);
      size_t o = ((size_t)(2048 + b)) * 512 + ng;
      Xthi[o] = hh; Xtlo[o] = ll;
      size_t o2 = ((size_t)(b * 512 + ng)) * LDB + 256;
      XShi[o2] = hh; XSlo[o2] = ll;
    }
  }
}

extern "C" void kernel_launch(void* const* d_in, const int* in_sizes, int n_in,
                              void* d_out, int out_size, void* d_ws, size_t ws_size,
                              hipStream_t stream) {
  const float* inputs = (const float*)d_in[0];
  const float* graph  = (const float*)d_in[1];
  const float* eWru = (const float*)d_in[2];
  const float* ebru = (const float*)d_in[3];
  const float* eWc  = (const float*)d_in[4];
  const float* ebc  = (const float*)d_in[5];
  const float* dWru = (const float*)d_in[6];
  const float* dbru = (const float*)d_in[7];
  const float* dWc  = (const float*)d_in[8];
  const float* dbc  = (const float*)d_in[9];
  const float* dWo  = (const float*)d_in[10];
  const float* dbo  = (const float*)d_in[11];
  float* out = (float*)d_out;

  char* w = (char*)d_ws;
  auto carve = [&](size_t bytes) {
    char* p = w; w += (bytes + 255) & ~(size_t)255; return p;
  };
  short* Tshi = (short*)carve((size_t)1536 * 512 * 2);
  short* Tslo = (short*)carve((size_t)1536 * 512 * 2);
  short* Xthi = (short*)carve((size_t)2176 * 512 * 2);
  short* Xtlo = (short*)carve((size_t)2176 * 512 * 2);
  short* X2hi = (short*)carve((size_t)2048 * 512 * 2);
  short* X2lo = (short*)carve((size_t)2048 * 512 * 2);
  short* XShi = (short*)carve((size_t)16384 * LDB * 2);
  short* XSlo = (short*)carve((size_t)16384 * LDB * 2);
  float* Ut   = (float*)carve((size_t)2048 * 512 * 4);
  float* TMP  = (float*)carve((size_t)512 * 512 * 4);
  float* TMP2 = (float*)carve((size_t)512 * 512 * 4);
  short* Bthi = (short*)carve((size_t)512 * 512 * 2);
  short* Btlo = (short*)carve((size_t)512 * 512 * 2);
  short* eWruHi = (short*)carve((size_t)128 * LDB * 2);
  short* eWruLo = (short*)carve((size_t)128 * LDB * 2);
  short* eWcHi  = (short*)carve((size_t)64 * LDB * 2);
  short* eWcLo  = (short*)carve((size_t)64 * LDB * 2);
  short* dWruHi = (short*)carve((size_t)128 * LDB * 2);
  short* dWruLo = (short*)carve((size_t)128 * LDB * 2);
  short* dWcHi  = (short*)carve((size_t)64 * LDB * 2);
  short* dWcLo  = (short*)carve((size_t)64 * LDB * 2);
  if ((size_t)(w - (char*)d_ws) > ws_size) return;

  dim3 blk(256);
  // zero Xt (h0 + x pads) and m0 slots of XS (h0)
  k_zeroxt<<<545, blk, 0, stream>>>((uint4*)Xthi, (uint4*)Xtlo, 139264);
  k_zerom0<<<512, blk, 0, stream>>>(XShi, XSlo);

  // T-stack [T1;T2;T3]
  k_prepT<<<1024, blk, 0, stream>>>(graph, Tshi, Tslo, 512 * 512);
  t512<<<dim3(16, 16), blk, 0, stream>>>(graph, Bthi, Btlo);
  gemm_bt<<<dim3(8, 4), blk, 0, stream>>>(Tshi, Tslo, Bthi, Btlo, TMP, 512,
                                          nullptr, nullptr, 0);
  k_cheb2b<<<1024, blk, 0, stream>>>(TMP, Tshi + 512 * 512, Tslo + 512 * 512);
  t512<<<dim3(16, 16), blk, 0, stream>>>(TMP, Bthi, Btlo);
  gemm_bt<<<dim3(8, 4), blk, 0, stream>>>(Tshi, Tslo, Bthi, Btlo, TMP2, 512,
                                          nullptr, nullptr, 0);
  k_cheb3b<<<1024, blk, 0, stream>>>(TMP2, graph, Tshi + 1024 * 512, Tslo + 1024 * 512);

  k_prepW<<<160, blk, 0, stream>>>(eWru, eWruHi, eWruLo, 128);
  k_prepW<<<80,  blk, 0, stream>>>(eWc,  eWcHi,  eWcLo,  64);
  k_prepW<<<160, blk, 0, stream>>>(dWru, dWruHi, dWruLo, 128);
  k_prepW<<<80,  blk, 0, stream>>>(dWc,  dWcHi,  dWcLo,  64);
  k_setx0<<<64, blk, 0, stream>>>(inputs, Xthi, Xtlo, XShi, XSlo);

  dim3 d1Grid(24, 17);     // h-rows + x-block ; 408 blocks (%8==0)
  dim3 d2Grid(24, 16);     // h-rows only ; 384 blocks (%8==0)
  dim3 mruGrid(8, 32, 2);  // n-tiles x b x j-half ; 512 blocks
  dim3 mcGrid(8, 32);

  for (int t = 0; t < 24; ++t) {
    bool enc = t < 12;
    const short* wruh = enc ? eWruHi : dWruHi;
    const short* wrul = enc ? eWruLo : dWruLo;
    const short* wch  = enc ? eWcHi  : dWcHi;
    const short* wcl  = enc ? eWcLo  : dWcLo;
    const float* bru  = enc ? ebru : dbru;
    const float* bc   = enc ? ebc  : dbc;

    gemm_bt<<<d1Grid, blk, 0, stream>>>(Xthi, Xtlo, Tshi, Tslo,
                                        nullptr, 0, XShi, XSlo, 1);
    k_mix_ru<<<mruGrid, blk, 0, stream>>>(wruh, wrul, XShi, XSlo, bru,
                                          Xthi, Xtlo, X2hi, X2lo, Ut);
    gemm_bt<<<d2Grid, blk, 0, stream>>>(X2hi, X2lo, Tshi, Tslo,
                                        nullptr, 0, XShi, XSlo, 1);
    if (enc) {
      const float* xs = (t < 11) ? inputs + (size_t)(t + 1) * 512 : nullptr;
      k_mix_c<<<mcGrid, blk, 0, stream>>>(wch, wcl, XShi, XSlo, bc, Ut,
                                          Xthi, Xtlo, 0, xs,
                                          nullptr, nullptr, nullptr, 0);
    } else {
      k_mix_c<<<mcGrid, blk, 0, stream>>>(wch, wcl, XShi, XSlo, bc, Ut,
                                          Xthi, Xtlo, 1, nullptr,
                                          dWo, dbo, out, t - 12);
    }
  }
}